// Round 4
// baseline (2149.548 us; speedup 1.0000x reference)
//
#include <hip/hip_runtime.h>
#include <hip/hip_bf16.h>
#include <math.h>

// Problem dims (fixed by reference)
#define B 32
#define S 256
#define H 768
#define KG 200
#define FF 3072
#define LH 128
#define D 968        // H + KG
#define DP 1024      // D padded to multiple of 32 (and N-pad for FF2 out)
#define NT 11
#define G4 512       // 4*LH
#define START_TAG 9
#define END_TAG 10
#define M_TOK 8192   // B*S

typedef __attribute__((ext_vector_type(8))) short short8;
typedef __attribute__((ext_vector_type(4))) float f32x4;

// ---------------------------------------------------------------------------
// async global->LDS, 16B per lane. LDS dest must be wave-uniform base;
// HW scatters lane i to base + i*16.
__device__ __forceinline__ void gl_lds16(const void* gptr, void* lptr) {
    __builtin_amdgcn_global_load_lds(
        (const __attribute__((address_space(1))) void*)gptr,
        (__attribute__((address_space(3))) void*)lptr,
        16, 0, 0);
}

// LDS-only barrier: drains LDS ops but NOT vmcnt (global loads/stores keep
// flying across it). __syncthreads would emit s_waitcnt vmcnt(0) and defeat
// the register prefetch of `pre` in the LSTM recurrence.
__device__ __forceinline__ void barrier_lds() {
    asm volatile("s_waitcnt lgkmcnt(0)\n\ts_barrier" ::: "memory");
}

// ---------------------------------------------------------------------------
// Kernel 1: kg projection + LayerNorm + tanh + attention score (per token)
#define TPB 8
__global__ __launch_bounds__(256) void kg_score_kernel(
    const float* __restrict__ in,      // (B,S,D)
    const float* __restrict__ W1,      // (H,KG)
    const float* __restrict__ b1,
    const float* __restrict__ ln_g,
    const float* __restrict__ ln_b,
    const float* __restrict__ W2,      // (1,H)
    const float* __restrict__ b2,
    float* __restrict__ scores)        // (B*S)
{
    __shared__ float kg_s[TPB][KG];
    __shared__ float red[256];
    __shared__ float red2[256];
    int tid = threadIdx.x;
    int tok0 = blockIdx.x * TPB;

    for (int i = tid; i < TPB * KG; i += 256) {
        int tk = i / KG, k = i % KG;
        kg_s[tk][k] = in[(size_t)(tok0 + tk) * D + H + k];
    }
    __syncthreads();

    float acc[3][TPB];
    for (int ii = 0; ii < 3; ++ii) {
        int i = ii * 256 + tid;          // 0..767
        float a[TPB];
        float bv = b1[i];
#pragma unroll
        for (int tk = 0; tk < TPB; ++tk) a[tk] = bv;
        for (int k = 0; k < KG; ++k) {
            float w = W1[(size_t)i * KG + k];
#pragma unroll
            for (int tk = 0; tk < TPB; ++tk) a[tk] += kg_s[tk][k] * w;
        }
#pragma unroll
        for (int tk = 0; tk < TPB; ++tk) acc[ii][tk] = a[tk];
    }
    float g3[3], bb3[3], w2[3];
    for (int ii = 0; ii < 3; ++ii) {
        int i = ii * 256 + tid;
        g3[ii] = ln_g[i]; bb3[ii] = ln_b[i]; w2[ii] = W2[i];
    }

    for (int tk = 0; tk < TPB; ++tk) {
        float s1 = acc[0][tk] + acc[1][tk] + acc[2][tk];
        float s2 = acc[0][tk]*acc[0][tk] + acc[1][tk]*acc[1][tk] + acc[2][tk]*acc[2][tk];
        red[tid] = s1; red2[tid] = s2;
        __syncthreads();
        for (int st = 128; st > 0; st >>= 1) {
            if (tid < st) { red[tid] += red[tid + st]; red2[tid] += red2[tid + st]; }
            __syncthreads();
        }
        float mu  = red[0] * (1.f / H);
        float var = red2[0] * (1.f / H) - mu * mu;
        float rstd = rsqrtf(var + 1e-5f);
        __syncthreads();
        float sc = 0.f;
#pragma unroll
        for (int ii = 0; ii < 3; ++ii)
            sc += tanhf((acc[ii][tk] - mu) * rstd * g3[ii] + bb3[ii]) * w2[ii];
        red[tid] = sc;
        __syncthreads();
        for (int st = 128; st > 0; st >>= 1) {
            if (tid < st) red[tid] += red[tid + st];
            __syncthreads();
        }
        if (tid == 0) scores[tok0 + tk] = red[0] + b2[0];
        __syncthreads();
    }
}

// ---------------------------------------------------------------------------
// Kernel 2: softmax over sequence dim per batch
__global__ __launch_bounds__(256) void softmax_kernel(
    const float* __restrict__ scores, float* __restrict__ attw)
{
    int b = blockIdx.x, tid = threadIdx.x;
    __shared__ float red[256];
    float v = scores[b * S + tid];
    red[tid] = v; __syncthreads();
    for (int st = 128; st > 0; st >>= 1) {
        if (tid < st) red[tid] = fmaxf(red[tid], red[tid + st]);
        __syncthreads();
    }
    float m = red[0]; __syncthreads();
    float e = expf(v - m);
    red[tid] = e; __syncthreads();
    for (int st = 128; st > 0; st >>= 1) {
        if (tid < st) red[tid] += red[tid + st];
        __syncthreads();
    }
    attw[b * S + tid] = e / red[0];
}

// ---------------------------------------------------------------------------
// Kernel 3: combined = [bert, kg*(1+attw)]; writes fp32 compact (stride D)
// AND bf16 K-padded (stride DP, pad cols zero) for the MFMA GEMM.
__global__ __launch_bounds__(256) void combine2_kernel(
    const float* __restrict__ in, const float* __restrict__ attw,
    float* __restrict__ comb32, __hip_bfloat16* __restrict__ Ab)
{
    size_t idx = (size_t)blockIdx.x * 256 + threadIdx.x;   // over M_TOK*DP
    if (idx >= (size_t)M_TOK * DP) return;
    int d = (int)(idx & (DP - 1));
    size_t tok = idx >> 10;
    if (d < D) {
        float v = in[tok * D + d];
        if (d >= H) v *= (1.f + attw[tok]);
        comb32[tok * D + d] = v;
        Ab[idx] = __float2bfloat16(v);
    } else {
        Ab[idx] = __float2bfloat16(0.f);
    }
}

// ---------------------------------------------------------------------------
// Weight cast: src (N,K) fp32 -> dst (Np,Kp) bf16, zero pad.
__global__ __launch_bounds__(256) void castpad2d_kernel(
    const float* __restrict__ src, __hip_bfloat16* __restrict__ dst,
    int N, int K, int Np, int Kp)
{
    size_t idx = (size_t)blockIdx.x * 256 + threadIdx.x;
    if (idx >= (size_t)Np * Kp) return;
    int n = (int)(idx / Kp), k = (int)(idx % Kp);
    float v = (n < N && k < K) ? src[(size_t)n * K + k] : 0.f;
    dst[idx] = __float2bfloat16(v);
}

__global__ __launch_bounds__(256) void cast1d_kernel(
    const float* __restrict__ src, __hip_bfloat16* __restrict__ dst, int n)
{
    int idx = blockIdx.x * 256 + threadIdx.x;
    if (idx < n) dst[idx] = __float2bfloat16(src[idx]);
}

// ---------------------------------------------------------------------------
// bf16 MFMA GEMM (m97 structure): C(M,Np) = act(A(M,Kp) @ W(Np,Kp)^T + bias)
//   [+ res fp32 (M,res_ld)], cols >= N_real forced to 0.
// flags: bit0 = relu, bit1 = bf16 output (else fp32).
__global__ __launch_bounds__(256) void mfma_gemm(
    const __hip_bfloat16* __restrict__ A,
    const __hip_bfloat16* __restrict__ Wb,
    const float* __restrict__ bias,
    const float* __restrict__ res, int res_ld,
    void* __restrict__ Cout,
    int Np, int Kp, int N_real, int flags)
{
    __shared__ short As[128 * 32];
    __shared__ short Bs[128 * 32];
    const int tid  = threadIdx.x;
    const int wave = tid >> 6;
    const int lane = tid & 63;
    const int bm = blockIdx.y * 128, bn = blockIdx.x * 128;
    const int sr = lane >> 2;           // 0..15
    const int sc = (lane & 3) * 8;      // 0,8,16,24
    const int fr = lane & 15;
    const int fq = lane >> 4;           // quad
    const int wm = (wave >> 1) * 64, wn = (wave & 1) * 64;

    f32x4 acc[4][4];
#pragma unroll
    for (int i = 0; i < 4; ++i)
#pragma unroll
        for (int j = 0; j < 4; ++j) acc[i][j] = (f32x4){0.f, 0.f, 0.f, 0.f};

    const __hip_bfloat16* ga0 = A  + (size_t)(bm + wave * 32      + sr) * Kp + sc;
    const __hip_bfloat16* ga1 = A  + (size_t)(bm + wave * 32 + 16 + sr) * Kp + sc;
    const __hip_bfloat16* gb0 = Wb + (size_t)(bn + wave * 32      + sr) * Kp + sc;
    const __hip_bfloat16* gb1 = Wb + (size_t)(bn + wave * 32 + 16 + sr) * Kp + sc;
    short* lA0 = &As[(wave * 2 + 0) * 512];
    short* lA1 = &As[(wave * 2 + 1) * 512];
    short* lB0 = &Bs[(wave * 2 + 0) * 512];
    short* lB1 = &Bs[(wave * 2 + 1) * 512];

    for (int k0 = 0; k0 < Kp; k0 += 32) {
        gl_lds16(ga0 + k0, lA0);
        gl_lds16(ga1 + k0, lA1);
        gl_lds16(gb0 + k0, lB0);
        gl_lds16(gb1 + k0, lB1);
        __syncthreads();   // compiler drains vmcnt(0) before s_barrier

        short8 af[4], bfr[4];
#pragma unroll
        for (int mi = 0; mi < 4; ++mi)
            af[mi] = *(const short8*)&As[(wm + mi * 16 + fr) * 32 + fq * 8];
#pragma unroll
        for (int ni = 0; ni < 4; ++ni)
            bfr[ni] = *(const short8*)&Bs[(wn + ni * 16 + fr) * 32 + fq * 8];
#pragma unroll
        for (int mi = 0; mi < 4; ++mi)
#pragma unroll
            for (int ni = 0; ni < 4; ++ni)
                acc[mi][ni] = __builtin_amdgcn_mfma_f32_16x16x32_bf16(
                    af[mi], bfr[ni], acc[mi][ni], 0, 0, 0);
        __syncthreads();
    }

    const bool relu = flags & 1;
    const bool obf  = flags & 2;
#pragma unroll
    for (int mi = 0; mi < 4; ++mi) {
#pragma unroll
        for (int ni = 0; ni < 4; ++ni) {
#pragma unroll
            for (int r = 0; r < 4; ++r) {
                int m = bm + wm + mi * 16 + fq * 4 + r;
                int n = bn + wn + ni * 16 + fr;
                float v = acc[mi][ni][r];
                if (n < N_real) {
                    v += bias[n];
                    if (relu) v = fmaxf(v, 0.f);
                    if (res) v += res[(size_t)m * res_ld + n];
                } else {
                    v = 0.f;
                }
                if (obf)
                    ((__hip_bfloat16*)Cout)[(size_t)m * Np + n] = __float2bfloat16(v);
                else
                    ((float*)Cout)[(size_t)m * Np + n] = v;
            }
        }
    }
}

// ---------------------------------------------------------------------------
// small fp32 GEMM kept for emissions only (N=11, K=256)
#define BM 64
#define BN 64
#define BKK 16
__global__ __launch_bounds__(256) void gemm_kernel(
    const float* __restrict__ A, const float* __restrict__ W,
    const float* __restrict__ bias, const float* __restrict__ res,
    float* __restrict__ C, int M, int N, int K, int act)
{
    __shared__ float As[BKK][BM + 1];
    __shared__ float Ws[BKK][BN + 1];
    int bm = blockIdx.y * BM, bn = blockIdx.x * BN;
    int tid = threadIdx.x;
    int tm = (tid / 16) * 4;
    int tn = (tid % 16) * 4;
    float acc[4][4] = {};

    for (int k0 = 0; k0 < K; k0 += BKK) {
        for (int i = tid; i < BM * BKK; i += 256) {
            int m = i / BKK, k = i % BKK;
            float v = 0.f;
            if (k0 + k < K) v = A[(size_t)(bm + m) * K + k0 + k];
            As[k][m] = v;
        }
        for (int i = tid; i < BN * BKK; i += 256) {
            int n = i / BKK, k = i % BKK;
            float v = 0.f;
            if (bn + n < N && k0 + k < K) v = W[(size_t)(bn + n) * K + k0 + k];
            Ws[k][n] = v;
        }
        __syncthreads();
#pragma unroll
        for (int k = 0; k < BKK; ++k) {
            float a[4], w[4];
#pragma unroll
            for (int i = 0; i < 4; ++i) a[i] = As[k][tm + i];
#pragma unroll
            for (int j = 0; j < 4; ++j) w[j] = Ws[k][tn + j];
#pragma unroll
            for (int i = 0; i < 4; ++i)
#pragma unroll
                for (int j = 0; j < 4; ++j) acc[i][j] += a[i] * w[j];
        }
        __syncthreads();
    }
#pragma unroll
    for (int i = 0; i < 4; ++i) {
        int m = bm + tm + i;
        if (m >= M) continue;
#pragma unroll
        for (int j = 0; j < 4; ++j) {
            int n = bn + tn + j;
            if (n >= N) continue;
            float v = acc[i][j] + bias[n];
            if (act == 1) v = fmaxf(v, 0.f);
            if (res) v += res[(size_t)m * N + n];
            C[(size_t)m * N + n] = v;
        }
    }
}

// ---------------------------------------------------------------------------
// Batched MFMA LSTM recurrence.
// Grid = 4 blocks: (dir = blockIdx.x>>1, sample half s0 = (blockIdx.x&1)*16).
// Block = 512 threads = 8 waves; wave w owns hidden cols [16w,16w+16) for
// ALL four gate types, so i/f/g/o for a (sample,j) pair live in the same
// lane's accumulators (C layout: col=lane&15, row=quad*4+reg).
// Per step: gates(16x512) = h(16x128) @ Whh^T via mfma_f32_16x16x32_bf16;
// Whh held in B-fragments (64 VGPRs); h ping-pongs through LDS (bf16).
// `pre` (input projection) is register-prefetched one step ahead; barriers
// are LDS-only so the global loads/stores stream across steps.
__global__ __launch_bounds__(512) void lstm_mfma_kernel(
    const float* __restrict__ pre_f, const float* __restrict__ pre_b,
    const __hip_bfloat16* __restrict__ whh_f,
    const __hip_bfloat16* __restrict__ whh_b,
    void* __restrict__ out, int out_bf16)   // out: (B,S,2*LH)
{
    const int dir = blockIdx.x >> 1;
    const int s0  = (blockIdx.x & 1) * 16;
    const float* pre = dir ? pre_b : pre_f;
    const __hip_bfloat16* whh = dir ? whh_b : whh_f;

    const int tid  = threadIdx.x;
    const int wave = tid >> 6;          // 0..7
    const int lane = tid & 63;
    const int l15  = lane & 15;         // C col / A row index
    const int q    = lane >> 4;         // quad
    const int col  = 16 * wave + l15;   // hidden index [0,128)

    // B fragments: bf[t][kt] = Whh[t*128+col][kt*32 + q*8 .. +7]
    short8 bf[4][4];
#pragma unroll
    for (int t = 0; t < 4; ++t) {
        const __hip_bfloat16* wrow = whh + (size_t)(t * 128 + col) * LH;
#pragma unroll
        for (int kt = 0; kt < 4; ++kt)
            bf[t][kt] = *(const short8*)(wrow + kt * 32 + q * 8);
    }

    // ping-pong h buffers, row stride 136 (pad 8) to break b128 bank aliasing
    __shared__ __hip_bfloat16 h_lds[2][16][136];
    for (int i = tid; i < 2 * 16 * 136; i += 512)
        ((__hip_bfloat16*)h_lds)[i] = __float2bfloat16(0.f);

    f32x4 c = {0.f, 0.f, 0.f, 0.f};

    // per-lane pre pointers: sample s = s0+4q+r, gate g = t*128+col
    const float* pp[4];
#pragma unroll
    for (int r = 0; r < 4; ++r)
        pp[r] = pre + ((size_t)(s0 + 4 * q + r) * S + (dir ? (S - 1) : 0)) * G4 + col;
    const int stepoff = dir ? -G4 : G4;

    float pcur[4][4];                   // [gate type][r]
#pragma unroll
    for (int t = 0; t < 4; ++t)
#pragma unroll
        for (int r = 0; r < 4; ++r)
            pcur[t][r] = pp[r][t * 128];

    barrier_lds();
    int p = 0;

    for (int step = 0; step < S; ++step) {
        // prefetch next step's pre into registers (latency hidden: consumed
        // next iteration; barrier below does NOT drain vmcnt)
        float pnxt[4][4];
#pragma unroll
        for (int t = 0; t < 4; ++t)
#pragma unroll
            for (int r = 0; r < 4; ++r) pnxt[t][r] = 0.f;
        if (step + 1 < S) {
#pragma unroll
            for (int r = 0; r < 4; ++r) pp[r] += stepoff;
#pragma unroll
            for (int t = 0; t < 4; ++t)
#pragma unroll
                for (int r = 0; r < 4; ++r)
                    pnxt[t][r] = pp[r][t * 128];
        }

        // A fragments: A[m=l15][k = kt*32 + q*8 ..]
        short8 af[4];
#pragma unroll
        for (int kt = 0; kt < 4; ++kt)
            af[kt] = *(const short8*)&h_lds[p][l15][kt * 32 + q * 8];

        f32x4 acc[4];
#pragma unroll
        for (int t = 0; t < 4; ++t) {
            acc[t] = (f32x4){0.f, 0.f, 0.f, 0.f};
#pragma unroll
            for (int kt = 0; kt < 4; ++kt)
                acc[t] = __builtin_amdgcn_mfma_f32_16x16x32_bf16(
                    af[kt], bf[t][kt], acc[t], 0, 0, 0);
        }

        const int tcur = dir ? (S - 1 - step) : step;
        float hnew[4];
#pragma unroll
        for (int r = 0; r < 4; ++r) {
            float iv = acc[0][r] + pcur[0][r];
            float fv = acc[1][r] + pcur[1][r];
            float gv = acc[2][r] + pcur[2][r];
            float ov = acc[3][r] + pcur[3][r];
            float ig = 1.f / (1.f + expf(-iv));
            float fg = 1.f / (1.f + expf(-fv));
            float gg = tanhf(gv);
            float og = 1.f / (1.f + expf(-ov));
            float cc = fg * c[r] + ig * gg;
            c[r] = cc;
            hnew[r] = og * tanhf(cc);
        }

        // write new h into the OTHER buffer (ping-pong: current buffer's
        // reads were consumed by mfma issue above, so no read/write hazard
        // within this step) + stream to global out.
#pragma unroll
        for (int r = 0; r < 4; ++r) {
            __hip_bfloat16 hb = __float2bfloat16(hnew[r]);
            h_lds[p ^ 1][4 * q + r][col] = hb;
            size_t tok = (size_t)(s0 + 4 * q + r) * S + tcur;
            if (out_bf16)
                ((__hip_bfloat16*)out)[tok * 256 + dir * 128 + col] = hb;
            else
                ((float*)out)[tok * 256 + dir * 128 + col] = hnew[r];
        }
        barrier_lds();
        p ^= 1;
#pragma unroll
        for (int t = 0; t < 4; ++t)
#pragma unroll
            for (int r = 0; r < 4; ++r) pcur[t][r] = pnxt[t][r];
    }
}

// ---------------------------------------------------------------------------
// CRF NLL per sample
__global__ __launch_bounds__(64) void crf_kernel(
    const float* __restrict__ em, const int* __restrict__ labels,
    const int* __restrict__ mask, const float* __restrict__ trans,
    float* __restrict__ nll)
{
    int b = blockIdx.x, tid = threadIdx.x;
    __shared__ float tr[NT * NT];
    __shared__ float alpha[NT];
    __shared__ float red[64];
    __shared__ float gold_s;

    for (int i = tid; i < NT * NT; i += 64) tr[i] = trans[i];
    __syncthreads();

    float emit = 0.f, pair = 0.f, lenf = 0.f;
    for (int s = tid; s < S; s += 64) {
        int lab = labels[b * S + s];
        float mf = (float)mask[b * S + s];
        emit += em[(size_t)(b * S + s) * NT + lab] * mf;
        lenf += mf;
        if (s >= 1) {
            int lp = labels[b * S + s - 1];
            pair += tr[lp * NT + lab] * mf;
        }
    }
    red[tid] = emit; __syncthreads();
    for (int st = 32; st > 0; st >>= 1) { if (tid < st) red[tid] += red[tid + st]; __syncthreads(); }
    float emit_tot = red[0]; __syncthreads();
    red[tid] = pair; __syncthreads();
    for (int st = 32; st > 0; st >>= 1) { if (tid < st) red[tid] += red[tid + st]; __syncthreads(); }
    float pair_tot = red[0]; __syncthreads();
    red[tid] = lenf; __syncthreads();
    for (int st = 32; st > 0; st >>= 1) { if (tid < st) red[tid] += red[tid + st]; __syncthreads(); }
    float len_tot = red[0]; __syncthreads();

    if (tid == 0) {
        int len_i = (int)(len_tot + 0.5f);
        int last = labels[b * S + len_i - 1];
        gold_s = tr[START_TAG * NT + labels[b * S]] + emit_tot + pair_tot
               + tr[last * NT + END_TAG];
    }
    if (tid < NT) alpha[tid] = tr[START_TAG * NT + tid] + em[(size_t)(b * S) * NT + tid];
    __syncthreads();

    for (int t = 1; t < S; ++t) {
        float newv = 0.f;
        if (tid < NT) {
            float vals[NT];
            float m = -1e30f;
#pragma unroll
            for (int i2 = 0; i2 < NT; ++i2) {
                float v = alpha[i2] + tr[i2 * NT + tid];
                vals[i2] = v;
                m = fmaxf(m, v);
            }
            float ssum = 0.f;
#pragma unroll
            for (int i2 = 0; i2 < NT; ++i2) ssum += expf(vals[i2] - m);
            newv = m + logf(ssum) + em[(size_t)(b * S + t) * NT + tid];
            if (!(mask[b * S + t] > 0)) newv = alpha[tid];
        }
        __syncthreads();
        if (tid < NT) alpha[tid] = newv;
        __syncthreads();
    }

    if (tid < NT) red[tid] = alpha[tid] + tr[tid * NT + END_TAG];
    __syncthreads();
    if (tid == 0) {
        float m = -1e30f;
        for (int j = 0; j < NT; ++j) m = fmaxf(m, red[j]);
        float ssum = 0.f;
        for (int j = 0; j < NT; ++j) ssum += expf(red[j] - m);
        float logZ = m + logf(ssum);
        nll[b] = logZ - gold_s;
    }
}

__global__ void mean_kernel(const float* __restrict__ nll, float* __restrict__ out)
{
    if (threadIdx.x == 0) {
        float s = 0.f;
        for (int i = 0; i < B; ++i) s += nll[i];
        out[0] = s / (float)B;
    }
}

// ---------------------------------------------------------------------------
extern "C" void kernel_launch(void* const* d_in, const int* in_sizes, int n_in,
                              void* d_out, int out_size, void* d_ws, size_t ws_size,
                              hipStream_t stream)
{
    const float* in_emb = (const float*)d_in[0];
    const int*   mask   = (const int*)d_in[1];
    const int*   labels = (const int*)d_in[2];
    const float* kg_W1  = (const float*)d_in[3];
    const float* kg_b1  = (const float*)d_in[4];
    const float* ln_g   = (const float*)d_in[5];
    const float* ln_b   = (const float*)d_in[6];
    const float* kg_W2  = (const float*)d_in[7];
    const float* kg_b2  = (const float*)d_in[8];
    const float* ff_W1  = (const float*)d_in[9];
    const float* ff_b1  = (const float*)d_in[10];
    const float* ff_W2  = (const float*)d_in[11];
    const float* ff_b2  = (const float*)d_in[12];
    const float* Wih0f  = (const float*)d_in[13];
    const float* Whh0f  = (const float*)d_in[14];
    const float* b0f    = (const float*)d_in[15];
    const float* Wih0b  = (const float*)d_in[16];
    const float* Whh0b  = (const float*)d_in[17];
    const float* b0b    = (const float*)d_in[18];
    const float* Wih1f  = (const float*)d_in[19];
    const float* Whh1f  = (const float*)d_in[20];
    const float* b1f    = (const float*)d_in[21];
    const float* Wih1b  = (const float*)d_in[22];
    const float* Whh1b  = (const float*)d_in[23];
    const float* b1b    = (const float*)d_in[24];
    const float* cls_W  = (const float*)d_in[25];
    const float* cls_b  = (const float*)d_in[26];
    const float* trans  = (const float*)d_in[27];
    (void)ws_size; (void)in_sizes; (void)n_in; (void)out_size;

    // ---- workspace arena ----
    char* wsb = (char*)d_ws;
    size_t o = 0;
    float*          comb32 = (float*)(wsb + o);            o += (size_t)M_TOK * D  * 4;  // 31,719,424
    __hip_bfloat16* Ab     = (__hip_bfloat16*)(wsb + o);   size_t ab_off = o; o += (size_t)M_TOK * DP * 2;  // 16,777,216
    char*           big    = wsb + o;                      o += (size_t)M_TOK * FF * 2;  // 50,331,648
    __hip_bfloat16* xb     = (__hip_bfloat16*)(wsb + o);   o += (size_t)M_TOK * DP * 2;  // 16,777,216
    __hip_bfloat16* Wbff1  = (__hip_bfloat16*)(wsb + o);   o += (size_t)FF * DP * 2;     // 6,291,456
    __hip_bfloat16* Wbff2  = (__hip_bfloat16*)(wsb + o);   o += (size_t)DP * FF * 2;     // 6,291,456
    __hip_bfloat16* Wb0f   = (__hip_bfloat16*)(wsb + o);   o += (size_t)G4 * DP * 2;     // 1,048,576
    __hip_bfloat16* Wb0b   = (__hip_bfloat16*)(wsb + o);   o += (size_t)G4 * DP * 2;
    __hip_bfloat16* Wb1f   = (__hip_bfloat16*)(wsb + o);   o += (size_t)G4 * 256 * 2;    // 262,144
    __hip_bfloat16* Wb1b   = (__hip_bfloat16*)(wsb + o);   o += (size_t)G4 * 256 * 2;
    __hip_bfloat16* Whb0f  = (__hip_bfloat16*)(wsb + o);   o += (size_t)G4 * LH * 2;     // 131,072
    __hip_bfloat16* Whb0b  = (__hip_bfloat16*)(wsb + o);   o += (size_t)G4 * LH * 2;
    __hip_bfloat16* Whb1f  = (__hip_bfloat16*)(wsb + o);   o += (size_t)G4 * LH * 2;
    __hip_bfloat16* Whb1b  = (__hip_bfloat16*)(wsb + o);   o += (size_t)G4 * LH * 2;
    float*          scores = (float*)(wsb + o);            o += (size_t)M_TOK * 4;
    float*          attw   = (float*)(wsb + o);            o += (size_t)M_TOK * 4;
    float*          emis   = (float*)(wsb + o);            o += (size_t)M_TOK * NT * 4;
    float*          nll    = (float*)(wsb + o);            o += B * 4;
    // big region reuse timeline:
    __hip_bfloat16* ff1b  = (__hip_bfloat16*)big;                      // FF1 out (dead after FF2)
    float*          pre0f = (float*)(big + 0);                         // after FF2
    float*          pre0b = (float*)(big + 16777216);
    __hip_bfloat16* x1b   = (__hip_bfloat16*)(big + 33554432);         // LSTM0 out bf16 (4 MiB)
    float*          pre1f = (float*)(big + 0);                         // after LSTM0
    float*          pre1b = (float*)(big + 16777216);
    float*          x2    = (float*)(wsb + ab_off);                    // reuse Ab (dead after FF1)

    // ---- weight casts (independent; read inputs only) ----
    castpad2d_kernel<<<(FF * DP + 255) / 256, 256, 0, stream>>>(ff_W1, Wbff1, FF, D,  FF, DP);
    castpad2d_kernel<<<(DP * FF + 255) / 256, 256, 0, stream>>>(ff_W2, Wbff2, D,  FF, DP, FF);
    castpad2d_kernel<<<(G4 * DP + 255) / 256, 256, 0, stream>>>(Wih0f, Wb0f, G4, D, G4, DP);
    castpad2d_kernel<<<(G4 * DP + 255) / 256, 256, 0, stream>>>(Wih0b, Wb0b, G4, D, G4, DP);
    castpad2d_kernel<<<(G4 * 256 + 255) / 256, 256, 0, stream>>>(Wih1f, Wb1f, G4, 256, G4, 256);
    castpad2d_kernel<<<(G4 * 256 + 255) / 256, 256, 0, stream>>>(Wih1b, Wb1b, G4, 256, G4, 256);
    cast1d_kernel<<<(G4 * LH + 255) / 256, 256, 0, stream>>>(Whh0f, Whb0f, G4 * LH);
    cast1d_kernel<<<(G4 * LH + 255) / 256, 256, 0, stream>>>(Whh0b, Whb0b, G4 * LH);
    cast1d_kernel<<<(G4 * LH + 255) / 256, 256, 0, stream>>>(Whh1f, Whb1f, G4 * LH);
    cast1d_kernel<<<(G4 * LH + 255) / 256, 256, 0, stream>>>(Whh1b, Whb1b, G4 * LH);

    // ---- attention front-end ----
    kg_score_kernel<<<M_TOK / TPB, 256, 0, stream>>>(
        in_emb, kg_W1, kg_b1, ln_g, ln_b, kg_W2, kg_b2, scores);
    softmax_kernel<<<B, 256, 0, stream>>>(scores, attw);
    combine2_kernel<<<(M_TOK * DP + 255) / 256, 256, 0, stream>>>(in_emb, attw, comb32, Ab);

    // ---- FF block (bf16 MFMA) ----
    mfma_gemm<<<dim3(FF / 128, M_TOK / 128), 256, 0, stream>>>(
        Ab, Wbff1, ff_b1, nullptr, 0, ff1b, FF, DP, FF, 1 | 2);
    mfma_gemm<<<dim3(DP / 128, M_TOK / 128), 256, 0, stream>>>(
        ff1b, Wbff2, ff_b2, comb32, D, xb, DP, FF, D, 2);

    // ---- LSTM layer 0 ----
    mfma_gemm<<<dim3(G4 / 128, M_TOK / 128), 256, 0, stream>>>(
        xb, Wb0f, b0f, nullptr, 0, pre0f, G4, DP, G4, 0);
    mfma_gemm<<<dim3(G4 / 128, M_TOK / 128), 256, 0, stream>>>(
        xb, Wb0b, b0b, nullptr, 0, pre0b, G4, DP, G4, 0);
    lstm_mfma_kernel<<<4, 512, 0, stream>>>(pre0f, pre0b, Whb0f, Whb0b, x1b, 1);

    // ---- LSTM layer 1 ----
    mfma_gemm<<<dim3(G4 / 128, M_TOK / 128), 256, 0, stream>>>(
        x1b, Wb1f, b1f, nullptr, 0, pre1f, G4, 256, G4, 0);
    mfma_gemm<<<dim3(G4 / 128, M_TOK / 128), 256, 0, stream>>>(
        x1b, Wb1b, b1b, nullptr, 0, pre1b, G4, 256, G4, 0);
    lstm_mfma_kernel<<<4, 512, 0, stream>>>(pre1f, pre1b, Whb1f, Whb1b, x2, 0);

    // ---- emissions (tiny, fp32) + CRF + mean ----
    gemm_kernel<<<dim3(1, M_TOK / BM), 256, 0, stream>>>(
        x2, cls_W, cls_b, nullptr, emis, M_TOK, NT, 2 * LH, 0);
    crf_kernel<<<B, 64, 0, stream>>>(emis, labels, mask, trans, nll);
    mean_kernel<<<1, 64, 0, stream>>>(nll, (float*)d_out);
}

// Round 5
// 1416.220 us; speedup vs baseline: 1.5178x; 1.5178x over previous
//
#include <hip/hip_runtime.h>
#include <hip/hip_bf16.h>
#include <math.h>

// Problem dims (fixed by reference)
#define B 32
#define S 256
#define H 768
#define KG 200
#define FF 3072
#define LH 128
#define D 968        // H + KG
#define DP 1024      // D padded to multiple of 32 (and N-pad for FF2 out)
#define NT 11
#define G4 512       // 4*LH
#define START_TAG 9
#define END_TAG 10
#define M_TOK 8192   // B*S

typedef __attribute__((ext_vector_type(8))) short short8;
typedef __attribute__((ext_vector_type(4))) float f32x4;

// ---------------------------------------------------------------------------
// async global->LDS, 16B per lane.
__device__ __forceinline__ void gl_lds16(const void* gptr, void* lptr) {
    __builtin_amdgcn_global_load_lds(
        (const __attribute__((address_space(1))) void*)gptr,
        (__attribute__((address_space(3))) void*)lptr,
        16, 0, 0);
}

// LDS-only barrier: drains LDS ops but NOT vmcnt (global loads/stores keep
// flying across it).
__device__ __forceinline__ void barrier_lds() {
    asm volatile("s_waitcnt lgkmcnt(0)\n\ts_barrier" ::: "memory");
}

// Fast transcendentals (hardware v_exp_f32 / v_rcp_f32).
// Saturation: x->+inf: exp->inf, rcp(inf)=0. x->-inf: exp->0.
__device__ __forceinline__ float fsigmoid(float x) {
    return __builtin_amdgcn_rcpf(1.f + __expf(-x));
}
__device__ __forceinline__ float ftanh(float x) {
    return 1.f - 2.f * __builtin_amdgcn_rcpf(__expf(2.f * x) + 1.f);
}

// ---------------------------------------------------------------------------
// Kernel 1: kg projection + LayerNorm + tanh + attention score (per token)
#define TPB 8
__global__ __launch_bounds__(256) void kg_score_kernel(
    const float* __restrict__ in,      // (B,S,D)
    const float* __restrict__ W1,      // (H,KG)
    const float* __restrict__ b1,
    const float* __restrict__ ln_g,
    const float* __restrict__ ln_b,
    const float* __restrict__ W2,      // (1,H)
    const float* __restrict__ b2,
    float* __restrict__ scores)        // (B*S)
{
    __shared__ float kg_s[TPB][KG];
    __shared__ float red[256];
    __shared__ float red2[256];
    int tid = threadIdx.x;
    int tok0 = blockIdx.x * TPB;

    for (int i = tid; i < TPB * KG; i += 256) {
        int tk = i / KG, k = i % KG;
        kg_s[tk][k] = in[(size_t)(tok0 + tk) * D + H + k];
    }
    __syncthreads();

    float acc[3][TPB];
    for (int ii = 0; ii < 3; ++ii) {
        int i = ii * 256 + tid;          // 0..767
        float a[TPB];
        float bv = b1[i];
#pragma unroll
        for (int tk = 0; tk < TPB; ++tk) a[tk] = bv;
        for (int k = 0; k < KG; ++k) {
            float w = W1[(size_t)i * KG + k];
#pragma unroll
            for (int tk = 0; tk < TPB; ++tk) a[tk] += kg_s[tk][k] * w;
        }
#pragma unroll
        for (int tk = 0; tk < TPB; ++tk) acc[ii][tk] = a[tk];
    }
    float g3[3], bb3[3], w2[3];
    for (int ii = 0; ii < 3; ++ii) {
        int i = ii * 256 + tid;
        g3[ii] = ln_g[i]; bb3[ii] = ln_b[i]; w2[ii] = W2[i];
    }

    for (int tk = 0; tk < TPB; ++tk) {
        float s1 = acc[0][tk] + acc[1][tk] + acc[2][tk];
        float s2 = acc[0][tk]*acc[0][tk] + acc[1][tk]*acc[1][tk] + acc[2][tk]*acc[2][tk];
        red[tid] = s1; red2[tid] = s2;
        __syncthreads();
        for (int st = 128; st > 0; st >>= 1) {
            if (tid < st) { red[tid] += red[tid + st]; red2[tid] += red2[tid + st]; }
            __syncthreads();
        }
        float mu  = red[0] * (1.f / H);
        float var = red2[0] * (1.f / H) - mu * mu;
        float rstd = rsqrtf(var + 1e-5f);
        __syncthreads();
        float sc = 0.f;
#pragma unroll
        for (int ii = 0; ii < 3; ++ii)
            sc += tanhf((acc[ii][tk] - mu) * rstd * g3[ii] + bb3[ii]) * w2[ii];
        red[tid] = sc;
        __syncthreads();
        for (int st = 128; st > 0; st >>= 1) {
            if (tid < st) red[tid] += red[tid + st];
            __syncthreads();
        }
        if (tid == 0) scores[tok0 + tk] = red[0] + b2[0];
        __syncthreads();
    }
}

// ---------------------------------------------------------------------------
// Kernel 2: softmax over sequence dim per batch
__global__ __launch_bounds__(256) void softmax_kernel(
    const float* __restrict__ scores, float* __restrict__ attw)
{
    int b = blockIdx.x, tid = threadIdx.x;
    __shared__ float red[256];
    float v = scores[b * S + tid];
    red[tid] = v; __syncthreads();
    for (int st = 128; st > 0; st >>= 1) {
        if (tid < st) red[tid] = fmaxf(red[tid], red[tid + st]);
        __syncthreads();
    }
    float m = red[0]; __syncthreads();
    float e = expf(v - m);
    red[tid] = e; __syncthreads();
    for (int st = 128; st > 0; st >>= 1) {
        if (tid < st) red[tid] += red[tid + st];
        __syncthreads();
    }
    attw[b * S + tid] = e / red[0];
}

// ---------------------------------------------------------------------------
// Kernel 3: combined = [bert, kg*(1+attw)]; fp32 compact + bf16 K-padded.
__global__ __launch_bounds__(256) void combine2_kernel(
    const float* __restrict__ in, const float* __restrict__ attw,
    float* __restrict__ comb32, __hip_bfloat16* __restrict__ Ab)
{
    size_t idx = (size_t)blockIdx.x * 256 + threadIdx.x;   // over M_TOK*DP
    if (idx >= (size_t)M_TOK * DP) return;
    int d = (int)(idx & (DP - 1));
    size_t tok = idx >> 10;
    if (d < D) {
        float v = in[tok * D + d];
        if (d >= H) v *= (1.f + attw[tok]);
        comb32[tok * D + d] = v;
        Ab[idx] = __float2bfloat16(v);
    } else {
        Ab[idx] = __float2bfloat16(0.f);
    }
}

// ---------------------------------------------------------------------------
// Weight cast: src (N,K) fp32 -> dst (Np,Kp) bf16, zero pad.
__global__ __launch_bounds__(256) void castpad2d_kernel(
    const float* __restrict__ src, __hip_bfloat16* __restrict__ dst,
    int N, int K, int Np, int Kp)
{
    size_t idx = (size_t)blockIdx.x * 256 + threadIdx.x;
    if (idx >= (size_t)Np * Kp) return;
    int n = (int)(idx / Kp), k = (int)(idx % Kp);
    float v = (n < N && k < K) ? src[(size_t)n * K + k] : 0.f;
    dst[idx] = __float2bfloat16(v);
}

__global__ __launch_bounds__(256) void cast1d_kernel(
    const float* __restrict__ src, __hip_bfloat16* __restrict__ dst, int n)
{
    int idx = blockIdx.x * 256 + threadIdx.x;
    if (idx < n) dst[idx] = __float2bfloat16(src[idx]);
}

// ---------------------------------------------------------------------------
// bf16 MFMA GEMM: C(M,Np) = act(A(M,Kp) @ W(Np,Kp)^T + bias) [+ res].
// flags: bit0 = relu, bit1 = bf16 out, bit2 = LSTM gate-interleaved fp32
// store: C[m][ (n&127)*4 + (n>>7) ] (requires Np==512) so the recurrence
// reads (i,f,g,o) for one (tok,col) as one float4.
__global__ __launch_bounds__(256) void mfma_gemm(
    const __hip_bfloat16* __restrict__ A,
    const __hip_bfloat16* __restrict__ Wb,
    const float* __restrict__ bias,
    const float* __restrict__ res, int res_ld,
    void* __restrict__ Cout,
    int Np, int Kp, int N_real, int flags)
{
    __shared__ short As[128 * 32];
    __shared__ short Bs[128 * 32];
    const int tid  = threadIdx.x;
    const int wave = tid >> 6;
    const int lane = tid & 63;
    const int bm = blockIdx.y * 128, bn = blockIdx.x * 128;
    const int sr = lane >> 2;           // 0..15
    const int sc = (lane & 3) * 8;      // 0,8,16,24
    const int fr = lane & 15;
    const int fq = lane >> 4;           // quad
    const int wm = (wave >> 1) * 64, wn = (wave & 1) * 64;

    f32x4 acc[4][4];
#pragma unroll
    for (int i = 0; i < 4; ++i)
#pragma unroll
        for (int j = 0; j < 4; ++j) acc[i][j] = (f32x4){0.f, 0.f, 0.f, 0.f};

    const __hip_bfloat16* ga0 = A  + (size_t)(bm + wave * 32      + sr) * Kp + sc;
    const __hip_bfloat16* ga1 = A  + (size_t)(bm + wave * 32 + 16 + sr) * Kp + sc;
    const __hip_bfloat16* gb0 = Wb + (size_t)(bn + wave * 32      + sr) * Kp + sc;
    const __hip_bfloat16* gb1 = Wb + (size_t)(bn + wave * 32 + 16 + sr) * Kp + sc;
    short* lA0 = &As[(wave * 2 + 0) * 512];
    short* lA1 = &As[(wave * 2 + 1) * 512];
    short* lB0 = &Bs[(wave * 2 + 0) * 512];
    short* lB1 = &Bs[(wave * 2 + 1) * 512];

    for (int k0 = 0; k0 < Kp; k0 += 32) {
        gl_lds16(ga0 + k0, lA0);
        gl_lds16(ga1 + k0, lA1);
        gl_lds16(gb0 + k0, lB0);
        gl_lds16(gb1 + k0, lB1);
        __syncthreads();

        short8 af[4], bfr[4];
#pragma unroll
        for (int mi = 0; mi < 4; ++mi)
            af[mi] = *(const short8*)&As[(wm + mi * 16 + fr) * 32 + fq * 8];
#pragma unroll
        for (int ni = 0; ni < 4; ++ni)
            bfr[ni] = *(const short8*)&Bs[(wn + ni * 16 + fr) * 32 + fq * 8];
#pragma unroll
        for (int mi = 0; mi < 4; ++mi)
#pragma unroll
            for (int ni = 0; ni < 4; ++ni)
                acc[mi][ni] = __builtin_amdgcn_mfma_f32_16x16x32_bf16(
                    af[mi], bfr[ni], acc[mi][ni], 0, 0, 0);
        __syncthreads();
    }

    const bool relu = flags & 1;
    const bool obf  = flags & 2;
    const bool gate = flags & 4;
#pragma unroll
    for (int mi = 0; mi < 4; ++mi) {
#pragma unroll
        for (int ni = 0; ni < 4; ++ni) {
#pragma unroll
            for (int r = 0; r < 4; ++r) {
                int m = bm + wm + mi * 16 + fq * 4 + r;
                int n = bn + wn + ni * 16 + fr;
                float v = acc[mi][ni][r];
                if (n < N_real) {
                    v += bias[n];
                    if (relu) v = fmaxf(v, 0.f);
                    if (res) v += res[(size_t)m * res_ld + n];
                } else {
                    v = 0.f;
                }
                if (gate) {
                    ((float*)Cout)[(size_t)m * Np + ((n & 127) << 2) + (n >> 7)] = v;
                } else if (obf) {
                    ((__hip_bfloat16*)Cout)[(size_t)m * Np + n] = __float2bfloat16(v);
                } else {
                    ((float*)Cout)[(size_t)m * Np + n] = v;
                }
            }
        }
    }
}

// ---------------------------------------------------------------------------
// small fp32 GEMM kept for emissions only (N=11, K=256)
#define BM 64
#define BN 64
#define BKK 16
__global__ __launch_bounds__(256) void gemm_kernel(
    const float* __restrict__ A, const float* __restrict__ W,
    const float* __restrict__ bias, const float* __restrict__ res,
    float* __restrict__ C, int M, int N, int K, int act)
{
    __shared__ float As[BKK][BM + 1];
    __shared__ float Ws[BKK][BN + 1];
    int bm = blockIdx.y * BM, bn = blockIdx.x * BN;
    int tid = threadIdx.x;
    int tm = (tid / 16) * 4;
    int tn = (tid % 16) * 4;
    float acc[4][4] = {};

    for (int k0 = 0; k0 < K; k0 += BKK) {
        for (int i = tid; i < BM * BKK; i += 256) {
            int m = i / BKK, k = i % BKK;
            float v = 0.f;
            if (k0 + k < K) v = A[(size_t)(bm + m) * K + k0 + k];
            As[k][m] = v;
        }
        for (int i = tid; i < BN * BKK; i += 256) {
            int n = i / BKK, k = i % BKK;
            float v = 0.f;
            if (bn + n < N && k0 + k < K) v = W[(size_t)(bn + n) * K + k0 + k];
            Ws[k][n] = v;
        }
        __syncthreads();
#pragma unroll
        for (int k = 0; k < BKK; ++k) {
            float a[4], w[4];
#pragma unroll
            for (int i = 0; i < 4; ++i) a[i] = As[k][tm + i];
#pragma unroll
            for (int j = 0; j < 4; ++j) w[j] = Ws[k][tn + j];
#pragma unroll
            for (int i = 0; i < 4; ++i)
#pragma unroll
                for (int j = 0; j < 4; ++j) acc[i][j] += a[i] * w[j];
        }
        __syncthreads();
    }
#pragma unroll
    for (int i = 0; i < 4; ++i) {
        int m = bm + tm + i;
        if (m >= M) continue;
#pragma unroll
        for (int j = 0; j < 4; ++j) {
            int n = bn + tn + j;
            if (n >= N) continue;
            float v = acc[i][j] + bias[n];
            if (act == 1) v = fmaxf(v, 0.f);
            if (res) v += res[(size_t)m * N + n];
            C[(size_t)m * N + n] = v;
        }
    }
}

// ---------------------------------------------------------------------------
// Batched MFMA LSTM recurrence.
// Grid = 4 blocks: (dir = blockIdx.x>>1, sample half s0 = (blockIdx.x&1)*16).
// pre2 layout: (tok, col, gate) float4 per (tok,col) -> one dwordx4/lane/step
// (written by mfma_gemm flag bit2). Fast HW transcendentals for the gates.
__global__ __launch_bounds__(512) void lstm_mfma_kernel(
    const float* __restrict__ pre_f, const float* __restrict__ pre_b,
    const __hip_bfloat16* __restrict__ whh_f,
    const __hip_bfloat16* __restrict__ whh_b,
    void* __restrict__ out, int out_bf16)   // out: (B,S,2*LH)
{
    const int dir = blockIdx.x >> 1;
    const int s0  = (blockIdx.x & 1) * 16;
    const float* pre = dir ? pre_b : pre_f;
    const __hip_bfloat16* whh = dir ? whh_b : whh_f;

    const int tid  = threadIdx.x;
    const int wave = tid >> 6;          // 0..7
    const int lane = tid & 63;
    const int l15  = lane & 15;         // C col / A row index
    const int q    = lane >> 4;         // quad
    const int col  = 16 * wave + l15;   // hidden index [0,128)

    // B fragments: bf[t][kt] = Whh[t*128+col][kt*32 + q*8 .. +7]
    short8 bf[4][4];
#pragma unroll
    for (int t = 0; t < 4; ++t) {
        const __hip_bfloat16* wrow = whh + (size_t)(t * 128 + col) * LH;
#pragma unroll
        for (int kt = 0; kt < 4; ++kt)
            bf[t][kt] = *(const short8*)(wrow + kt * 32 + q * 8);
    }

    // ping-pong h buffers, row stride 136 bf16 (pad 8)
    __shared__ __hip_bfloat16 h_lds[2][16][136];
    for (int i = tid; i < 2 * 16 * 136; i += 512)
        ((__hip_bfloat16*)h_lds)[i] = __float2bfloat16(0.f);

    f32x4 c = {0.f, 0.f, 0.f, 0.f};

    // per-lane pre2 pointers: sample s0+4q+r, (col) -> float4 of gates
    const float* pp[4];
#pragma unroll
    for (int r = 0; r < 4; ++r)
        pp[r] = pre + ((size_t)(s0 + 4 * q + r) * S + (dir ? (S - 1) : 0)) * G4
                    + col * 4;
    const int stepoff = dir ? -G4 : G4;

    float4 pc[4];
#pragma unroll
    for (int r = 0; r < 4; ++r) pc[r] = *(const float4*)pp[r];

    barrier_lds();
    int p = 0;

    for (int step = 0; step < S; ++step) {
        // prefetch next step's pre (consumed next iteration; barrier below
        // does not drain vmcnt, so these stay in flight)
        float4 pn[4];
#pragma unroll
        for (int r = 0; r < 4; ++r) pn[r] = make_float4(0.f, 0.f, 0.f, 0.f);
        if (step + 1 < S) {
#pragma unroll
            for (int r = 0; r < 4; ++r) {
                pp[r] += stepoff;
                pn[r] = *(const float4*)pp[r];
            }
        }

        // A fragments from LDS
        short8 af[4];
#pragma unroll
        for (int kt = 0; kt < 4; ++kt)
            af[kt] = *(const short8*)&h_lds[p][l15][kt * 32 + q * 8];

        f32x4 acc[4];
#pragma unroll
        for (int t = 0; t < 4; ++t) {
            acc[t] = (f32x4){0.f, 0.f, 0.f, 0.f};
#pragma unroll
            for (int kt = 0; kt < 4; ++kt)
                acc[t] = __builtin_amdgcn_mfma_f32_16x16x32_bf16(
                    af[kt], bf[t][kt], acc[t], 0, 0, 0);
        }

        const int tcur = dir ? (S - 1 - step) : step;
        float hnew[4];
#pragma unroll
        for (int r = 0; r < 4; ++r) {
            float ig = fsigmoid(acc[0][r] + pc[r].x);
            float fg = fsigmoid(acc[1][r] + pc[r].y);
            float gg = ftanh   (acc[2][r] + pc[r].z);
            float og = fsigmoid(acc[3][r] + pc[r].w);
            float cc = fg * c[r] + ig * gg;
            c[r] = cc;
            hnew[r] = og * ftanh(cc);
        }

#pragma unroll
        for (int r = 0; r < 4; ++r) {
            __hip_bfloat16 hb = __float2bfloat16(hnew[r]);
            h_lds[p ^ 1][4 * q + r][col] = hb;
            size_t tok = (size_t)(s0 + 4 * q + r) * S + tcur;
            if (out_bf16)
                ((__hip_bfloat16*)out)[tok * 256 + dir * 128 + col] = hb;
            else
                ((float*)out)[tok * 256 + dir * 128 + col] = hnew[r];
        }
        barrier_lds();
        p ^= 1;
#pragma unroll
        for (int r = 0; r < 4; ++r) pc[r] = pn[r];
    }
}

// ---------------------------------------------------------------------------
// CRF NLL per sample (fast __expf/__logf in the 255-step recursion)
__global__ __launch_bounds__(64) void crf_kernel(
    const float* __restrict__ em, const int* __restrict__ labels,
    const int* __restrict__ mask, const float* __restrict__ trans,
    float* __restrict__ nll)
{
    int b = blockIdx.x, tid = threadIdx.x;
    __shared__ float tr[NT * NT];
    __shared__ float alpha[NT];
    __shared__ float red[64];
    __shared__ float gold_s;

    for (int i = tid; i < NT * NT; i += 64) tr[i] = trans[i];
    __syncthreads();

    float emit = 0.f, pair = 0.f, lenf = 0.f;
    for (int s = tid; s < S; s += 64) {
        int lab = labels[b * S + s];
        float mf = (float)mask[b * S + s];
        emit += em[(size_t)(b * S + s) * NT + lab] * mf;
        lenf += mf;
        if (s >= 1) {
            int lp = labels[b * S + s - 1];
            pair += tr[lp * NT + lab] * mf;
        }
    }
    red[tid] = emit; __syncthreads();
    for (int st = 32; st > 0; st >>= 1) { if (tid < st) red[tid] += red[tid + st]; __syncthreads(); }
    float emit_tot = red[0]; __syncthreads();
    red[tid] = pair; __syncthreads();
    for (int st = 32; st > 0; st >>= 1) { if (tid < st) red[tid] += red[tid + st]; __syncthreads(); }
    float pair_tot = red[0]; __syncthreads();
    red[tid] = lenf; __syncthreads();
    for (int st = 32; st > 0; st >>= 1) { if (tid < st) red[tid] += red[tid + st]; __syncthreads(); }
    float len_tot = red[0]; __syncthreads();

    if (tid == 0) {
        int len_i = (int)(len_tot + 0.5f);
        int last = labels[b * S + len_i - 1];
        gold_s = tr[START_TAG * NT + labels[b * S]] + emit_tot + pair_tot
               + tr[last * NT + END_TAG];
    }
    if (tid < NT) alpha[tid] = tr[START_TAG * NT + tid] + em[(size_t)(b * S) * NT + tid];
    __syncthreads();

    for (int t = 1; t < S; ++t) {
        float newv = 0.f;
        if (tid < NT) {
            float vals[NT];
            float m = -1e30f;
#pragma unroll
            for (int i2 = 0; i2 < NT; ++i2) {
                float v = alpha[i2] + tr[i2 * NT + tid];
                vals[i2] = v;
                m = fmaxf(m, v);
            }
            float ssum = 0.f;
#pragma unroll
            for (int i2 = 0; i2 < NT; ++i2) ssum += __expf(vals[i2] - m);
            newv = m + __logf(ssum) + em[(size_t)(b * S + t) * NT + tid];
            if (!(mask[b * S + t] > 0)) newv = alpha[tid];
        }
        __syncthreads();
        if (tid < NT) alpha[tid] = newv;
        __syncthreads();
    }

    if (tid < NT) red[tid] = alpha[tid] + tr[tid * NT + END_TAG];
    __syncthreads();
    if (tid == 0) {
        float m = -1e30f;
        for (int j = 0; j < NT; ++j) m = fmaxf(m, red[j]);
        float ssum = 0.f;
        for (int j = 0; j < NT; ++j) ssum += __expf(red[j] - m);
        float logZ = m + __logf(ssum);
        nll[b] = logZ - gold_s;
    }
}

__global__ void mean_kernel(const float* __restrict__ nll, float* __restrict__ out)
{
    if (threadIdx.x == 0) {
        float s = 0.f;
        for (int i = 0; i < B; ++i) s += nll[i];
        out[0] = s / (float)B;
    }
}

// ---------------------------------------------------------------------------
extern "C" void kernel_launch(void* const* d_in, const int* in_sizes, int n_in,
                              void* d_out, int out_size, void* d_ws, size_t ws_size,
                              hipStream_t stream)
{
    const float* in_emb = (const float*)d_in[0];
    const int*   mask   = (const int*)d_in[1];
    const int*   labels = (const int*)d_in[2];
    const float* kg_W1  = (const float*)d_in[3];
    const float* kg_b1  = (const float*)d_in[4];
    const float* ln_g   = (const float*)d_in[5];
    const float* ln_b   = (const float*)d_in[6];
    const float* kg_W2  = (const float*)d_in[7];
    const float* kg_b2  = (const float*)d_in[8];
    const float* ff_W1  = (const float*)d_in[9];
    const float* ff_b1  = (const float*)d_in[10];
    const float* ff_W2  = (const float*)d_in[11];
    const float* ff_b2  = (const float*)d_in[12];
    const float* Wih0f  = (const float*)d_in[13];
    const float* Whh0f  = (const float*)d_in[14];
    const float* b0f    = (const float*)d_in[15];
    const float* Wih0b  = (const float*)d_in[16];
    const float* Whh0b  = (const float*)d_in[17];
    const float* b0b    = (const float*)d_in[18];
    const float* Wih1f  = (const float*)d_in[19];
    const float* Whh1f  = (const float*)d_in[20];
    const float* b1f    = (const float*)d_in[21];
    const float* Wih1b  = (const float*)d_in[22];
    const float* Whh1b  = (const float*)d_in[23];
    const float* b1b    = (const float*)d_in[24];
    const float* cls_W  = (const float*)d_in[25];
    const float* cls_b  = (const float*)d_in[26];
    const float* trans  = (const float*)d_in[27];
    (void)ws_size; (void)in_sizes; (void)n_in; (void)out_size;

    // ---- workspace arena ----
    char* wsb = (char*)d_ws;
    size_t o = 0;
    float*          comb32 = (float*)(wsb + o);            o += (size_t)M_TOK * D  * 4;
    __hip_bfloat16* Ab     = (__hip_bfloat16*)(wsb + o);   size_t ab_off = o; o += (size_t)M_TOK * DP * 2;
    char*           big    = wsb + o;                      o += (size_t)M_TOK * FF * 2;
    __hip_bfloat16* xb     = (__hip_bfloat16*)(wsb + o);   o += (size_t)M_TOK * DP * 2;
    __hip_bfloat16* Wbff1  = (__hip_bfloat16*)(wsb + o);   o += (size_t)FF * DP * 2;
    __hip_bfloat16* Wbff2  = (__hip_bfloat16*)(wsb + o);   o += (size_t)DP * FF * 2;
    __hip_bfloat16* Wb0f   = (__hip_bfloat16*)(wsb + o);   o += (size_t)G4 * DP * 2;
    __hip_bfloat16* Wb0b   = (__hip_bfloat16*)(wsb + o);   o += (size_t)G4 * DP * 2;
    __hip_bfloat16* Wb1f   = (__hip_bfloat16*)(wsb + o);   o += (size_t)G4 * 256 * 2;
    __hip_bfloat16* Wb1b   = (__hip_bfloat16*)(wsb + o);   o += (size_t)G4 * 256 * 2;
    __hip_bfloat16* Whb0f  = (__hip_bfloat16*)(wsb + o);   o += (size_t)G4 * LH * 2;
    __hip_bfloat16* Whb0b  = (__hip_bfloat16*)(wsb + o);   o += (size_t)G4 * LH * 2;
    __hip_bfloat16* Whb1f  = (__hip_bfloat16*)(wsb + o);   o += (size_t)G4 * LH * 2;
    __hip_bfloat16* Whb1b  = (__hip_bfloat16*)(wsb + o);   o += (size_t)G4 * LH * 2;
    float*          scores = (float*)(wsb + o);            o += (size_t)M_TOK * 4;
    float*          attw   = (float*)(wsb + o);            o += (size_t)M_TOK * 4;
    float*          emis   = (float*)(wsb + o);            o += (size_t)M_TOK * NT * 4;
    float*          nll    = (float*)(wsb + o);            o += B * 4;
    // big region reuse timeline:
    __hip_bfloat16* ff1b  = (__hip_bfloat16*)big;                      // FF1 out
    float*          pre0f = (float*)(big + 0);                         // after FF2
    float*          pre0b = (float*)(big + 16777216);
    __hip_bfloat16* x1b   = (__hip_bfloat16*)(big + 33554432);         // LSTM0 out
    float*          pre1f = (float*)(big + 0);                         // after LSTM0
    float*          pre1b = (float*)(big + 16777216);
    float*          x2    = (float*)(wsb + ab_off);                    // reuse Ab

    // ---- weight casts ----
    castpad2d_kernel<<<(FF * DP + 255) / 256, 256, 0, stream>>>(ff_W1, Wbff1, FF, D,  FF, DP);
    castpad2d_kernel<<<(DP * FF + 255) / 256, 256, 0, stream>>>(ff_W2, Wbff2, D,  FF, DP, FF);
    castpad2d_kernel<<<(G4 * DP + 255) / 256, 256, 0, stream>>>(Wih0f, Wb0f, G4, D, G4, DP);
    castpad2d_kernel<<<(G4 * DP + 255) / 256, 256, 0, stream>>>(Wih0b, Wb0b, G4, D, G4, DP);
    castpad2d_kernel<<<(G4 * 256 + 255) / 256, 256, 0, stream>>>(Wih1f, Wb1f, G4, 256, G4, 256);
    castpad2d_kernel<<<(G4 * 256 + 255) / 256, 256, 0, stream>>>(Wih1b, Wb1b, G4, 256, G4, 256);
    cast1d_kernel<<<(G4 * LH + 255) / 256, 256, 0, stream>>>(Whh0f, Whb0f, G4 * LH);
    cast1d_kernel<<<(G4 * LH + 255) / 256, 256, 0, stream>>>(Whh0b, Whb0b, G4 * LH);
    cast1d_kernel<<<(G4 * LH + 255) / 256, 256, 0, stream>>>(Whh1f, Whb1f, G4 * LH);
    cast1d_kernel<<<(G4 * LH + 255) / 256, 256, 0, stream>>>(Whh1b, Whb1b, G4 * LH);

    // ---- attention front-end ----
    kg_score_kernel<<<M_TOK / TPB, 256, 0, stream>>>(
        in_emb, kg_W1, kg_b1, ln_g, ln_b, kg_W2, kg_b2, scores);
    softmax_kernel<<<B, 256, 0, stream>>>(scores, attw);
    combine2_kernel<<<(M_TOK * DP + 255) / 256, 256, 0, stream>>>(in_emb, attw, comb32, Ab);

    // ---- FF block (bf16 MFMA) ----
    mfma_gemm<<<dim3(FF / 128, M_TOK / 128), 256, 0, stream>>>(
        Ab, Wbff1, ff_b1, nullptr, 0, ff1b, FF, DP, FF, 1 | 2);
    mfma_gemm<<<dim3(DP / 128, M_TOK / 128), 256, 0, stream>>>(
        ff1b, Wbff2, ff_b2, comb32, D, xb, DP, FF, D, 2);

    // ---- LSTM layer 0 (pre in gate-interleaved layout, flag 4) ----
    mfma_gemm<<<dim3(G4 / 128, M_TOK / 128), 256, 0, stream>>>(
        xb, Wb0f, b0f, nullptr, 0, pre0f, G4, DP, G4, 4);
    mfma_gemm<<<dim3(G4 / 128, M_TOK / 128), 256, 0, stream>>>(
        xb, Wb0b, b0b, nullptr, 0, pre0b, G4, DP, G4, 4);
    lstm_mfma_kernel<<<4, 512, 0, stream>>>(pre0f, pre0b, Whb0f, Whb0b, x1b, 1);

    // ---- LSTM layer 1 ----
    mfma_gemm<<<dim3(G4 / 128, M_TOK / 128), 256, 0, stream>>>(
        x1b, Wb1f, b1f, nullptr, 0, pre1f, G4, 256, G4, 4);
    mfma_gemm<<<dim3(G4 / 128, M_TOK / 128), 256, 0, stream>>>(
        x1b, Wb1b, b1b, nullptr, 0, pre1b, G4, 256, G4, 4);
    lstm_mfma_kernel<<<4, 512, 0, stream>>>(pre1f, pre1b, Whb1f, Whb1b, x2, 0);

    // ---- emissions (tiny, fp32) + CRF + mean ----
    gemm_kernel<<<dim3(1, M_TOK / BM), 256, 0, stream>>>(
        x2, cls_W, cls_b, nullptr, emis, M_TOK, NT, 2 * LH, 0);
    crf_kernel<<<B, 64, 0, stream>>>(emis, labels, mask, trans, nll);
    mean_kernel<<<1, 64, 0, stream>>>(nll, (float*)d_out);
}

// Round 6
// 1331.035 us; speedup vs baseline: 1.6149x; 1.0640x over previous
//
#include <hip/hip_runtime.h>
#include <hip/hip_bf16.h>
#include <math.h>

// Problem dims (fixed by reference)
#define B 32
#define S 256
#define H 768
#define KG 200
#define KGP 224      // KG padded to x32
#define FF 3072
#define LH 128
#define D 968        // H + KG
#define DP 1024      // D padded to multiple of 32 (and N-pad for FF2 out)
#define NT 11
#define G4 512       // 4*LH
#define START_TAG 9
#define END_TAG 10
#define M_TOK 8192   // B*S

typedef __attribute__((ext_vector_type(8))) short short8;
typedef __attribute__((ext_vector_type(4))) float f32x4;

// ---------------------------------------------------------------------------
// async global->LDS, 16B per lane.
__device__ __forceinline__ void gl_lds16(const void* gptr, void* lptr) {
    __builtin_amdgcn_global_load_lds(
        (const __attribute__((address_space(1))) void*)gptr,
        (__attribute__((address_space(3))) void*)lptr,
        16, 0, 0);
}

// LDS-only barrier via BUILTINS (not inline asm): SIInsertWaitcnts models
// these precisely and does NOT add a conservative vmcnt(0) drain the way it
// does around "memory"-clobber inline asm (m131/m135: compiler defeats asm
// waitcnt; m139: raw s_barrier avoids the drain). 0xC07F = vmcnt(63),
// expcnt(7), lgkmcnt(0) -> waits LDS only; global loads/stores stay in
// flight across the barrier. sched_barrier(0) pins LDS op ordering.
__device__ __forceinline__ void barrier_lds() {
    __builtin_amdgcn_sched_barrier(0);
    __builtin_amdgcn_s_waitcnt(0xC07F);
    __builtin_amdgcn_s_barrier();
    __builtin_amdgcn_sched_barrier(0);
}

// Fast transcendentals (hardware v_exp_f32 / v_rcp_f32).
__device__ __forceinline__ float fsigmoid(float x) {
    return __builtin_amdgcn_rcpf(1.f + __expf(-x));
}
__device__ __forceinline__ float ftanh(float x) {
    return 1.f - 2.f * __builtin_amdgcn_rcpf(__expf(2.f * x) + 1.f);
}

// ---------------------------------------------------------------------------
// kg slice cast: Akg (M_TOK, KGP) bf16 from in_emb cols H..D, zero pad.
__global__ __launch_bounds__(256) void castpad_kg_kernel(
    const float* __restrict__ in, __hip_bfloat16* __restrict__ Akg)
{
    size_t idx = (size_t)blockIdx.x * 256 + threadIdx.x;
    if (idx >= (size_t)M_TOK * KGP) return;
    int k = (int)(idx % KGP);
    size_t tok = idx / KGP;
    float v = (k < KG) ? in[tok * D + H + k] : 0.f;
    Akg[idx] = __float2bfloat16(v);
}

// ---------------------------------------------------------------------------
// LayerNorm + tanh + W2-dot per token; one wave per token, shuffle reduce.
__global__ __launch_bounds__(256) void ln_score_kernel(
    const float* __restrict__ h32,     // (M_TOK, H)
    const float* __restrict__ ln_g, const float* __restrict__ ln_b,
    const float* __restrict__ W2, const float* __restrict__ b2,
    float* __restrict__ scores)
{
    int wave = threadIdx.x >> 6, lane = threadIdx.x & 63;
    int tok = blockIdx.x * 4 + wave;
    const float* hp = h32 + (size_t)tok * H;
    float v[12], s1 = 0.f, s2 = 0.f;
#pragma unroll
    for (int i = 0; i < 12; ++i) {
        v[i] = hp[i * 64 + lane];
        s1 += v[i]; s2 += v[i] * v[i];
    }
#pragma unroll
    for (int o = 32; o > 0; o >>= 1) {
        s1 += __shfl_xor(s1, o, 64);
        s2 += __shfl_xor(s2, o, 64);
    }
    float mu = s1 * (1.f / H);
    float var = s2 * (1.f / H) - mu * mu;
    float rstd = rsqrtf(var + 1e-5f);
    float sc = 0.f;
#pragma unroll
    for (int i = 0; i < 12; ++i) {
        int cidx = i * 64 + lane;
        sc += ftanh((v[i] - mu) * rstd * ln_g[cidx] + ln_b[cidx]) * W2[cidx];
    }
#pragma unroll
    for (int o = 32; o > 0; o >>= 1) sc += __shfl_xor(sc, o, 64);
    if (lane == 0) scores[tok] = sc + b2[0];
}

// ---------------------------------------------------------------------------
// softmax over sequence dim per batch
__global__ __launch_bounds__(256) void softmax_kernel(
    const float* __restrict__ scores, float* __restrict__ attw)
{
    int b = blockIdx.x, tid = threadIdx.x;
    __shared__ float red[256];
    float v = scores[b * S + tid];
    red[tid] = v; __syncthreads();
    for (int st = 128; st > 0; st >>= 1) {
        if (tid < st) red[tid] = fmaxf(red[tid], red[tid + st]);
        __syncthreads();
    }
    float m = red[0]; __syncthreads();
    float e = expf(v - m);
    red[tid] = e; __syncthreads();
    for (int st = 128; st > 0; st >>= 1) {
        if (tid < st) red[tid] += red[tid + st];
        __syncthreads();
    }
    attw[b * S + tid] = e / red[0];
}

// ---------------------------------------------------------------------------
// combined = [bert, kg*(1+attw)]; fp32 compact + bf16 K-padded.
__global__ __launch_bounds__(256) void combine2_kernel(
    const float* __restrict__ in, const float* __restrict__ attw,
    float* __restrict__ comb32, __hip_bfloat16* __restrict__ Ab)
{
    size_t idx = (size_t)blockIdx.x * 256 + threadIdx.x;   // over M_TOK*DP
    if (idx >= (size_t)M_TOK * DP) return;
    int d = (int)(idx & (DP - 1));
    size_t tok = idx >> 10;
    if (d < D) {
        float v = in[tok * D + d];
        if (d >= H) v *= (1.f + attw[tok]);
        comb32[tok * D + d] = v;
        Ab[idx] = __float2bfloat16(v);
    } else {
        Ab[idx] = __float2bfloat16(0.f);
    }
}

// ---------------------------------------------------------------------------
// Weight cast: src (N,K) fp32 -> dst (Np,Kp) bf16, zero pad.
__global__ __launch_bounds__(256) void castpad2d_kernel(
    const float* __restrict__ src, __hip_bfloat16* __restrict__ dst,
    int N, int K, int Np, int Kp)
{
    size_t idx = (size_t)blockIdx.x * 256 + threadIdx.x;
    if (idx >= (size_t)Np * Kp) return;
    int n = (int)(idx / Kp), k = (int)(idx % Kp);
    float v = (n < N && k < K) ? src[(size_t)n * K + k] : 0.f;
    dst[idx] = __float2bfloat16(v);
}

__global__ __launch_bounds__(256) void cast1d_kernel(
    const float* __restrict__ src, __hip_bfloat16* __restrict__ dst, int n)
{
    int idx = blockIdx.x * 256 + threadIdx.x;
    if (idx < n) dst[idx] = __float2bfloat16(src[idx]);
}

// ---------------------------------------------------------------------------
// bf16 MFMA GEMM: C(M,Np) = act(A(M,Kp) @ W(Np,Kp)^T + bias) [+ res].
// flags: bit0 relu; bit1 bf16 out; bit2 LSTM gate-interleave fp32 store
// C[m][(n&127)*4+(n>>7)] (Np==512); bit3 compact fp32 store at stride
// N_real, cols >= N_real dropped.
__global__ __launch_bounds__(256) void mfma_gemm(
    const __hip_bfloat16* __restrict__ A,
    const __hip_bfloat16* __restrict__ Wb,
    const float* __restrict__ bias,
    const float* __restrict__ res, int res_ld,
    void* __restrict__ Cout,
    int Np, int Kp, int N_real, int flags)
{
    __shared__ short As[128 * 32];
    __shared__ short Bs[128 * 32];
    const int tid  = threadIdx.x;
    const int wave = tid >> 6;
    const int lane = tid & 63;
    const int bm = blockIdx.y * 128, bn = blockIdx.x * 128;
    const int sr = lane >> 2;           // 0..15
    const int sc = (lane & 3) * 8;      // 0,8,16,24
    const int fr = lane & 15;
    const int fq = lane >> 4;           // quad
    const int wm = (wave >> 1) * 64, wn = (wave & 1) * 64;

    f32x4 acc[4][4];
#pragma unroll
    for (int i = 0; i < 4; ++i)
#pragma unroll
        for (int j = 0; j < 4; ++j) acc[i][j] = (f32x4){0.f, 0.f, 0.f, 0.f};

    const __hip_bfloat16* ga0 = A  + (size_t)(bm + wave * 32      + sr) * Kp + sc;
    const __hip_bfloat16* ga1 = A  + (size_t)(bm + wave * 32 + 16 + sr) * Kp + sc;
    const __hip_bfloat16* gb0 = Wb + (size_t)(bn + wave * 32      + sr) * Kp + sc;
    const __hip_bfloat16* gb1 = Wb + (size_t)(bn + wave * 32 + 16 + sr) * Kp + sc;
    short* lA0 = &As[(wave * 2 + 0) * 512];
    short* lA1 = &As[(wave * 2 + 1) * 512];
    short* lB0 = &Bs[(wave * 2 + 0) * 512];
    short* lB1 = &Bs[(wave * 2 + 1) * 512];

    for (int k0 = 0; k0 < Kp; k0 += 32) {
        gl_lds16(ga0 + k0, lA0);
        gl_lds16(ga1 + k0, lA1);
        gl_lds16(gb0 + k0, lB0);
        gl_lds16(gb1 + k0, lB1);
        __syncthreads();

        short8 af[4], bfr[4];
#pragma unroll
        for (int mi = 0; mi < 4; ++mi)
            af[mi] = *(const short8*)&As[(wm + mi * 16 + fr) * 32 + fq * 8];
#pragma unroll
        for (int ni = 0; ni < 4; ++ni)
            bfr[ni] = *(const short8*)&Bs[(wn + ni * 16 + fr) * 32 + fq * 8];
#pragma unroll
        for (int mi = 0; mi < 4; ++mi)
#pragma unroll
            for (int ni = 0; ni < 4; ++ni)
                acc[mi][ni] = __builtin_amdgcn_mfma_f32_16x16x32_bf16(
                    af[mi], bfr[ni], acc[mi][ni], 0, 0, 0);
        __syncthreads();
    }

    const bool relu = flags & 1;
    const bool obf  = flags & 2;
    const bool gate = flags & 4;
    const bool cmp  = flags & 8;
#pragma unroll
    for (int mi = 0; mi < 4; ++mi) {
#pragma unroll
        for (int ni = 0; ni < 4; ++ni) {
#pragma unroll
            for (int r = 0; r < 4; ++r) {
                int m = bm + wm + mi * 16 + fq * 4 + r;
                int n = bn + wn + ni * 16 + fr;
                float v = acc[mi][ni][r];
                if (n < N_real) {
                    v += bias[n];
                    if (relu) v = fmaxf(v, 0.f);
                    if (res) v += res[(size_t)m * res_ld + n];
                } else {
                    v = 0.f;
                }
                if (gate) {
                    ((float*)Cout)[(size_t)m * Np + ((n & 127) << 2) + (n >> 7)] = v;
                } else if (cmp) {
                    if (n < N_real)
                        ((float*)Cout)[(size_t)m * N_real + n] = v;
                } else if (obf) {
                    ((__hip_bfloat16*)Cout)[(size_t)m * Np + n] = __float2bfloat16(v);
                } else {
                    ((float*)Cout)[(size_t)m * Np + n] = v;
                }
            }
        }
    }
}

// ---------------------------------------------------------------------------
// Batched MFMA LSTM recurrence (4 blocks: dir x sample-half).
__global__ __launch_bounds__(512) void lstm_mfma_kernel(
    const float* __restrict__ pre_f, const float* __restrict__ pre_b,
    const __hip_bfloat16* __restrict__ whh_f,
    const __hip_bfloat16* __restrict__ whh_b,
    void* __restrict__ out, int out_bf16)   // out: (B,S,2*LH)
{
    const int dir = blockIdx.x >> 1;
    const int s0  = (blockIdx.x & 1) * 16;
    const float* pre = dir ? pre_b : pre_f;
    const __hip_bfloat16* whh = dir ? whh_b : whh_f;

    const int tid  = threadIdx.x;
    const int wave = tid >> 6;          // 0..7
    const int lane = tid & 63;
    const int l15  = lane & 15;         // C col / A row index
    const int q    = lane >> 4;         // quad
    const int col  = 16 * wave + l15;   // hidden index [0,128)

    // B fragments: bf[t][kt] = Whh[t*128+col][kt*32 + q*8 .. +7]
    short8 bf[4][4];
#pragma unroll
    for (int t = 0; t < 4; ++t) {
        const __hip_bfloat16* wrow = whh + (size_t)(t * 128 + col) * LH;
#pragma unroll
        for (int kt = 0; kt < 4; ++kt)
            bf[t][kt] = *(const short8*)(wrow + kt * 32 + q * 8);
    }

    // ping-pong h buffers, row stride 136 bf16 (pad 8)
    __shared__ __hip_bfloat16 h_lds[2][16][136];
    for (int i = tid; i < 2 * 16 * 136; i += 512)
        ((__hip_bfloat16*)h_lds)[i] = __float2bfloat16(0.f);

    f32x4 c = {0.f, 0.f, 0.f, 0.f};

    // per-lane gate-interleaved pre pointers: sample s0+4q+r, col -> float4
    const float* pp[4];
#pragma unroll
    for (int r = 0; r < 4; ++r)
        pp[r] = pre + ((size_t)(s0 + 4 * q + r) * S + (dir ? (S - 1) : 0)) * G4
                    + col * 4;
    const int stepoff = dir ? -G4 : G4;

    float4 pc[4];
#pragma unroll
    for (int r = 0; r < 4; ++r) pc[r] = *(const float4*)pp[r];

    barrier_lds();
    int p = 0;

    for (int step = 0; step < S; ++step) {
        // prefetch next step's pre (stays in flight across barrier_lds)
        float4 pn[4];
#pragma unroll
        for (int r = 0; r < 4; ++r) pn[r] = make_float4(0.f, 0.f, 0.f, 0.f);
        if (step + 1 < S) {
#pragma unroll
            for (int r = 0; r < 4; ++r) {
                pp[r] += stepoff;
                pn[r] = *(const float4*)pp[r];
            }
        }

        // A fragments from LDS
        short8 af[4];
#pragma unroll
        for (int kt = 0; kt < 4; ++kt)
            af[kt] = *(const short8*)&h_lds[p][l15][kt * 32 + q * 8];

        f32x4 acc[4];
#pragma unroll
        for (int t = 0; t < 4; ++t) {
            acc[t] = (f32x4){0.f, 0.f, 0.f, 0.f};
#pragma unroll
            for (int kt = 0; kt < 4; ++kt)
                acc[t] = __builtin_amdgcn_mfma_f32_16x16x32_bf16(
                    af[kt], bf[t][kt], acc[t], 0, 0, 0);
        }

        const int tcur = dir ? (S - 1 - step) : step;
        float hnew[4];
#pragma unroll
        for (int r = 0; r < 4; ++r) {
            float ig = fsigmoid(acc[0][r] + pc[r].x);
            float fg = fsigmoid(acc[1][r] + pc[r].y);
            float gg = ftanh   (acc[2][r] + pc[r].z);
            float og = fsigmoid(acc[3][r] + pc[r].w);
            float cc = fg * c[r] + ig * gg;
            c[r] = cc;
            hnew[r] = og * ftanh(cc);
        }

#pragma unroll
        for (int r = 0; r < 4; ++r) {
            __hip_bfloat16 hb = __float2bfloat16(hnew[r]);
            h_lds[p ^ 1][4 * q + r][col] = hb;
            size_t tok = (size_t)(s0 + 4 * q + r) * S + tcur;
            if (out_bf16)
                ((__hip_bfloat16*)out)[tok * 256 + dir * 128 + col] = hb;
            else
                ((float*)out)[tok * 256 + dir * 128 + col] = hnew[r];
        }
        barrier_lds();
        p ^= 1;
#pragma unroll
        for (int r = 0; r < 4; ++r) pc[r] = pn[r];
    }
}

// ---------------------------------------------------------------------------
// CRF NLL per sample
__global__ __launch_bounds__(64) void crf_kernel(
    const float* __restrict__ em, const int* __restrict__ labels,
    const int* __restrict__ mask, const float* __restrict__ trans,
    float* __restrict__ nll)
{
    int b = blockIdx.x, tid = threadIdx.x;
    __shared__ float tr[NT * NT];
    __shared__ float alpha[NT];
    __shared__ float red[64];
    __shared__ float gold_s;

    for (int i = tid; i < NT * NT; i += 64) tr[i] = trans[i];
    __syncthreads();

    float emit = 0.f, pair = 0.f, lenf = 0.f;
    for (int s = tid; s < S; s += 64) {
        int lab = labels[b * S + s];
        float mf = (float)mask[b * S + s];
        emit += em[(size_t)(b * S + s) * NT + lab] * mf;
        lenf += mf;
        if (s >= 1) {
            int lp = labels[b * S + s - 1];
            pair += tr[lp * NT + lab] * mf;
        }
    }
    red[tid] = emit; __syncthreads();
    for (int st = 32; st > 0; st >>= 1) { if (tid < st) red[tid] += red[tid + st]; __syncthreads(); }
    float emit_tot = red[0]; __syncthreads();
    red[tid] = pair; __syncthreads();
    for (int st = 32; st > 0; st >>= 1) { if (tid < st) red[tid] += red[tid + st]; __syncthreads(); }
    float pair_tot = red[0]; __syncthreads();
    red[tid] = lenf; __syncthreads();
    for (int st = 32; st > 0; st >>= 1) { if (tid < st) red[tid] += red[tid + st]; __syncthreads(); }
    float len_tot = red[0]; __syncthreads();

    if (tid == 0) {
        int len_i = (int)(len_tot + 0.5f);
        int last = labels[b * S + len_i - 1];
        gold_s = tr[START_TAG * NT + labels[b * S]] + emit_tot + pair_tot
               + tr[last * NT + END_TAG];
    }
    if (tid < NT) alpha[tid] = tr[START_TAG * NT + tid] + em[(size_t)(b * S) * NT + tid];
    __syncthreads();

    for (int t = 1; t < S; ++t) {
        float newv = 0.f;
        if (tid < NT) {
            float vals[NT];
            float m = -1e30f;
#pragma unroll
            for (int i2 = 0; i2 < NT; ++i2) {
                float v = alpha[i2] + tr[i2 * NT + tid];
                vals[i2] = v;
                m = fmaxf(m, v);
            }
            float ssum = 0.f;
#pragma unroll
            for (int i2 = 0; i2 < NT; ++i2) ssum += __expf(vals[i2] - m);
            newv = m + __logf(ssum) + em[(size_t)(b * S + t) * NT + tid];
            if (!(mask[b * S + t] > 0)) newv = alpha[tid];
        }
        __syncthreads();
        if (tid < NT) alpha[tid] = newv;
        __syncthreads();
    }

    if (tid < NT) red[tid] = alpha[tid] + tr[tid * NT + END_TAG];
    __syncthreads();
    if (tid == 0) {
        float m = -1e30f;
        for (int j = 0; j < NT; ++j) m = fmaxf(m, red[j]);
        float ssum = 0.f;
        for (int j = 0; j < NT; ++j) ssum += __expf(red[j] - m);
        float logZ = m + __logf(ssum);
        nll[b] = logZ - gold_s;
    }
}

__global__ void mean_kernel(const float* __restrict__ nll, float* __restrict__ out)
{
    if (threadIdx.x == 0) {
        float s = 0.f;
        for (int i = 0; i < B; ++i) s += nll[i];
        out[0] = s / (float)B;
    }
}

// ---------------------------------------------------------------------------
extern "C" void kernel_launch(void* const* d_in, const int* in_sizes, int n_in,
                              void* d_out, int out_size, void* d_ws, size_t ws_size,
                              hipStream_t stream)
{
    const float* in_emb = (const float*)d_in[0];
    const int*   mask   = (const int*)d_in[1];
    const int*   labels = (const int*)d_in[2];
    const float* kg_W1  = (const float*)d_in[3];
    const float* kg_b1  = (const float*)d_in[4];
    const float* ln_g   = (const float*)d_in[5];
    const float* ln_b   = (const float*)d_in[6];
    const float* kg_W2  = (const float*)d_in[7];
    const float* kg_b2  = (const float*)d_in[8];
    const float* ff_W1  = (const float*)d_in[9];
    const float* ff_b1  = (const float*)d_in[10];
    const float* ff_W2  = (const float*)d_in[11];
    const float* ff_b2  = (const float*)d_in[12];
    const float* Wih0f  = (const float*)d_in[13];
    const float* Whh0f  = (const float*)d_in[14];
    const float* b0f    = (const float*)d_in[15];
    const float* Wih0b  = (const float*)d_in[16];
    const float* Whh0b  = (const float*)d_in[17];
    const float* b0b    = (const float*)d_in[18];
    const float* Wih1f  = (const float*)d_in[19];
    const float* Whh1f  = (const float*)d_in[20];
    const float* b1f    = (const float*)d_in[21];
    const float* Wih1b  = (const float*)d_in[22];
    const float* Whh1b  = (const float*)d_in[23];
    const float* b1b    = (const float*)d_in[24];
    const float* cls_W  = (const float*)d_in[25];
    const float* cls_b  = (const float*)d_in[26];
    const float* trans  = (const float*)d_in[27];
    (void)ws_size; (void)in_sizes; (void)n_in; (void)out_size;

    // ---- workspace arena ----
    char* wsb = (char*)d_ws;
    size_t o = 0;
    float*          comb32 = (float*)(wsb + o);            o += (size_t)M_TOK * D  * 4;
    __hip_bfloat16* Ab     = (__hip_bfloat16*)(wsb + o);   size_t ab_off = o; o += (size_t)M_TOK * DP * 2;
    char*           big    = wsb + o;                      o += (size_t)M_TOK * FF * 2;
    __hip_bfloat16* xb     = (__hip_bfloat16*)(wsb + o);   o += (size_t)M_TOK * DP * 2;
    __hip_bfloat16* Wbff1  = (__hip_bfloat16*)(wsb + o);   o += (size_t)FF * DP * 2;
    __hip_bfloat16* Wbff2  = (__hip_bfloat16*)(wsb + o);   o += (size_t)DP * FF * 2;
    __hip_bfloat16* Wb0f   = (__hip_bfloat16*)(wsb + o);   o += (size_t)G4 * DP * 2;
    __hip_bfloat16* Wb0b   = (__hip_bfloat16*)(wsb + o);   o += (size_t)G4 * DP * 2;
    __hip_bfloat16* Wb1f   = (__hip_bfloat16*)(wsb + o);   o += (size_t)G4 * 256 * 2;
    __hip_bfloat16* Wb1b   = (__hip_bfloat16*)(wsb + o);   o += (size_t)G4 * 256 * 2;
    __hip_bfloat16* Whb0f  = (__hip_bfloat16*)(wsb + o);   o += (size_t)G4 * LH * 2;
    __hip_bfloat16* Whb0b  = (__hip_bfloat16*)(wsb + o);   o += (size_t)G4 * LH * 2;
    __hip_bfloat16* Whb1f  = (__hip_bfloat16*)(wsb + o);   o += (size_t)G4 * LH * 2;
    __hip_bfloat16* Whb1b  = (__hip_bfloat16*)(wsb + o);   o += (size_t)G4 * LH * 2;
    __hip_bfloat16* Wbkg1  = (__hip_bfloat16*)(wsb + o);   o += (size_t)H * KGP * 2;
    __hip_bfloat16* Wbcls  = (__hip_bfloat16*)(wsb + o);   o += (size_t)128 * 256 * 2;
    float*          scores = (float*)(wsb + o);            o += (size_t)M_TOK * 4;
    float*          attw   = (float*)(wsb + o);            o += (size_t)M_TOK * 4;
    float*          emis   = (float*)(wsb + o);            o += (size_t)M_TOK * NT * 4;
    float*          nll    = (float*)(wsb + o);            o += B * 4;
    // big region reuse timeline:
    float*          h32   = (float*)(big + 0);                         // kg proj out (25.2 MB)
    __hip_bfloat16* Akg   = (__hip_bfloat16*)(big + 33554432);         // kg bf16 in (3.7 MB)
    __hip_bfloat16* ff1b  = (__hip_bfloat16*)big;                      // FF1 out (50.3 MB)
    float*          pre0f = (float*)(big + 0);                         // after FF2
    float*          pre0b = (float*)(big + 16777216);
    __hip_bfloat16* x1b   = (__hip_bfloat16*)(big + 33554432);         // LSTM0 out (4.2 MB)
    float*          pre1f = (float*)(big + 0);                         // after LSTM0
    float*          pre1b = (float*)(big + 16777216);
    __hip_bfloat16* x2b   = (__hip_bfloat16*)(wsb + ab_off);           // LSTM1 out (4.2 MB, reuse Ab)

    // ---- weight casts ----
    castpad2d_kernel<<<(FF * DP + 255) / 256, 256, 0, stream>>>(ff_W1, Wbff1, FF, D,  FF, DP);
    castpad2d_kernel<<<(DP * FF + 255) / 256, 256, 0, stream>>>(ff_W2, Wbff2, D,  FF, DP, FF);
    castpad2d_kernel<<<(G4 * DP + 255) / 256, 256, 0, stream>>>(Wih0f, Wb0f, G4, D, G4, DP);
    castpad2d_kernel<<<(G4 * DP + 255) / 256, 256, 0, stream>>>(Wih0b, Wb0b, G4, D, G4, DP);
    castpad2d_kernel<<<(G4 * 256 + 255) / 256, 256, 0, stream>>>(Wih1f, Wb1f, G4, 256, G4, 256);
    castpad2d_kernel<<<(G4 * 256 + 255) / 256, 256, 0, stream>>>(Wih1b, Wb1b, G4, 256, G4, 256);
    cast1d_kernel<<<(G4 * LH + 255) / 256, 256, 0, stream>>>(Whh0f, Whb0f, G4 * LH);
    cast1d_kernel<<<(G4 * LH + 255) / 256, 256, 0, stream>>>(Whh0b, Whb0b, G4 * LH);
    cast1d_kernel<<<(G4 * LH + 255) / 256, 256, 0, stream>>>(Whh1f, Whb1f, G4 * LH);
    cast1d_kernel<<<(G4 * LH + 255) / 256, 256, 0, stream>>>(Whh1b, Whb1b, G4 * LH);
    castpad2d_kernel<<<(H * KGP + 255) / 256, 256, 0, stream>>>(kg_W1, Wbkg1, H, KG, H, KGP);
    castpad2d_kernel<<<(128 * 256 + 255) / 256, 256, 0, stream>>>(cls_W, Wbcls, NT, 256, 128, 256);

    // ---- attention front-end (kg proj via MFMA) ----
    castpad_kg_kernel<<<(M_TOK * KGP + 255) / 256, 256, 0, stream>>>(in_emb, Akg);
    mfma_gemm<<<dim3(H / 128, M_TOK / 128), 256, 0, stream>>>(
        Akg, Wbkg1, kg_b1, nullptr, 0, h32, H, KGP, H, 0);
    ln_score_kernel<<<M_TOK / 4, 256, 0, stream>>>(
        h32, ln_g, ln_b, kg_W2, kg_b2, scores);
    softmax_kernel<<<B, 256, 0, stream>>>(scores, attw);
    combine2_kernel<<<(M_TOK * DP + 255) / 256, 256, 0, stream>>>(in_emb, attw, comb32, Ab);

    // ---- FF block (bf16 MFMA) ----
    mfma_gemm<<<dim3(FF / 128, M_TOK / 128), 256, 0, stream>>>(
        Ab, Wbff1, ff_b1, nullptr, 0, ff1b, FF, DP, FF, 1 | 2);
    mfma_gemm<<<dim3(DP / 128, M_TOK / 128), 256, 0, stream>>>(
        ff1b, Wbff2, ff_b2, comb32, D, xb, DP, FF, D, 2);

    // ---- LSTM layer 0 (pre in gate-interleaved layout, flag 4) ----
    mfma_gemm<<<dim3(G4 / 128, M_TOK / 128), 256, 0, stream>>>(
        xb, Wb0f, b0f, nullptr, 0, pre0f, G4, DP, G4, 4);
    mfma_gemm<<<dim3(G4 / 128, M_TOK / 128), 256, 0, stream>>>(
        xb, Wb0b, b0b, nullptr, 0, pre0b, G4, DP, G4, 4);
    lstm_mfma_kernel<<<4, 512, 0, stream>>>(pre0f, pre0b, Whb0f, Whb0b, x1b, 1);

    // ---- LSTM layer 1 ----
    mfma_gemm<<<dim3(G4 / 128, M_TOK / 128), 256, 0, stream>>>(
        x1b, Wb1f, b1f, nullptr, 0, pre1f, G4, 256, G4, 4);
    mfma_gemm<<<dim3(G4 / 128, M_TOK / 128), 256, 0, stream>>>(
        x1b, Wb1b, b1b, nullptr, 0, pre1b, G4, 256, G4, 4);
    lstm_mfma_kernel<<<4, 512, 0, stream>>>(pre1f, pre1b, Whb1f, Whb1b, x2b, 1);

    // ---- emissions via MFMA (compact store, stride NT) + CRF + mean ----
    mfma_gemm<<<dim3(1, M_TOK / 128), 256, 0, stream>>>(
        x2b, Wbcls, cls_b, nullptr, 0, emis, 128, 256, NT, 8);
    crf_kernel<<<B, 64, 0, stream>>>(emis, labels, mask, trans, nll);
    mean_kernel<<<1, 64, 0, stream>>>(nll, (float*)d_out);
}

// Round 7
// 1245.524 us; speedup vs baseline: 1.7258x; 1.0687x over previous
//
#include <hip/hip_runtime.h>
#include <hip/hip_bf16.h>
#include <math.h>

// Problem dims (fixed by reference)
#define B 32
#define S 256
#define H 768
#define KG 200
#define KGP 224      // KG padded to x32
#define FF 3072
#define LH 128
#define D 968        // H + KG
#define DP 1024      // D padded to multiple of 32 (and N-pad for FF2 out)
#define NT 11
#define G4 512       // 4*LH
#define START_TAG 9
#define END_TAG 10
#define M_TOK 8192   // B*S

typedef __attribute__((ext_vector_type(8))) short short8;
typedef __attribute__((ext_vector_type(4))) float f32x4;

// ---------------------------------------------------------------------------
// async global->LDS, 16B per lane.
__device__ __forceinline__ void gl_lds16(const void* gptr, void* lptr) {
    __builtin_amdgcn_global_load_lds(
        (const __attribute__((address_space(1))) void*)gptr,
        (__attribute__((address_space(3))) void*)lptr,
        16, 0, 0);
}

// LDS-only barrier (lgkmcnt(0), vmcnt/expcnt unconstrained).
__device__ __forceinline__ void barrier_lds() {
    __builtin_amdgcn_sched_barrier(0);
    __builtin_amdgcn_s_waitcnt(0xC07F);
    __builtin_amdgcn_s_barrier();
    __builtin_amdgcn_sched_barrier(0);
}

// Fast transcendentals (hardware v_exp_f32 / v_rcp_f32).
__device__ __forceinline__ float fsigmoid(float x) {
    return __builtin_amdgcn_rcpf(1.f + __expf(-x));
}
__device__ __forceinline__ float ftanh(float x) {
    return 1.f - 2.f * __builtin_amdgcn_rcpf(__expf(2.f * x) + 1.f);
}

// ---------------------------------------------------------------------------
// kg slice cast: Akg (M_TOK, KGP) bf16 from in_emb cols H..D, zero pad.
__global__ __launch_bounds__(256) void castpad_kg_kernel(
    const float* __restrict__ in, __hip_bfloat16* __restrict__ Akg)
{
    size_t idx = (size_t)blockIdx.x * 256 + threadIdx.x;
    if (idx >= (size_t)M_TOK * KGP) return;
    int k = (int)(idx % KGP);
    size_t tok = idx / KGP;
    float v = (k < KG) ? in[tok * D + H + k] : 0.f;
    Akg[idx] = __float2bfloat16(v);
}

// ---------------------------------------------------------------------------
// LayerNorm + tanh + W2-dot per token; one wave per token, shuffle reduce.
__global__ __launch_bounds__(256) void ln_score_kernel(
    const float* __restrict__ h32,     // (M_TOK, H)
    const float* __restrict__ ln_g, const float* __restrict__ ln_b,
    const float* __restrict__ W2, const float* __restrict__ b2,
    float* __restrict__ scores)
{
    int wave = threadIdx.x >> 6, lane = threadIdx.x & 63;
    int tok = blockIdx.x * 4 + wave;
    const float* hp = h32 + (size_t)tok * H;
    float v[12], s1 = 0.f, s2 = 0.f;
#pragma unroll
    for (int i = 0; i < 12; ++i) {
        v[i] = hp[i * 64 + lane];
        s1 += v[i]; s2 += v[i] * v[i];
    }
#pragma unroll
    for (int o = 32; o > 0; o >>= 1) {
        s1 += __shfl_xor(s1, o, 64);
        s2 += __shfl_xor(s2, o, 64);
    }
    float mu = s1 * (1.f / H);
    float var = s2 * (1.f / H) - mu * mu;
    float rstd = rsqrtf(var + 1e-5f);
    float sc = 0.f;
#pragma unroll
    for (int i = 0; i < 12; ++i) {
        int cidx = i * 64 + lane;
        sc += ftanh((v[i] - mu) * rstd * ln_g[cidx] + ln_b[cidx]) * W2[cidx];
    }
#pragma unroll
    for (int o = 32; o > 0; o >>= 1) sc += __shfl_xor(sc, o, 64);
    if (lane == 0) scores[tok] = sc + b2[0];
}

// ---------------------------------------------------------------------------
// softmax over sequence dim per batch
__global__ __launch_bounds__(256) void softmax_kernel(
    const float* __restrict__ scores, float* __restrict__ attw)
{
    int b = blockIdx.x, tid = threadIdx.x;
    __shared__ float red[256];
    float v = scores[b * S + tid];
    red[tid] = v; __syncthreads();
    for (int st = 128; st > 0; st >>= 1) {
        if (tid < st) red[tid] = fmaxf(red[tid], red[tid + st]);
        __syncthreads();
    }
    float m = red[0]; __syncthreads();
    float e = expf(v - m);
    red[tid] = e; __syncthreads();
    for (int st = 128; st > 0; st >>= 1) {
        if (tid < st) red[tid] += red[tid + st];
        __syncthreads();
    }
    attw[b * S + tid] = e / red[0];
}

// ---------------------------------------------------------------------------
// combined = [bert, kg*(1+attw)]; fp32 compact + bf16 K-padded.
__global__ __launch_bounds__(256) void combine2_kernel(
    const float* __restrict__ in, const float* __restrict__ attw,
    float* __restrict__ comb32, __hip_bfloat16* __restrict__ Ab)
{
    size_t idx = (size_t)blockIdx.x * 256 + threadIdx.x;   // over M_TOK*DP
    if (idx >= (size_t)M_TOK * DP) return;
    int d = (int)(idx & (DP - 1));
    size_t tok = idx >> 10;
    if (d < D) {
        float v = in[tok * D + d];
        if (d >= H) v *= (1.f + attw[tok]);
        comb32[tok * D + d] = v;
        Ab[idx] = __float2bfloat16(v);
    } else {
        Ab[idx] = __float2bfloat16(0.f);
    }
}

// ---------------------------------------------------------------------------
// Weight cast: src (N,K) fp32 -> dst (Np,Kp) bf16, zero pad.
__global__ __launch_bounds__(256) void castpad2d_kernel(
    const float* __restrict__ src, __hip_bfloat16* __restrict__ dst,
    int N, int K, int Np, int Kp)
{
    size_t idx = (size_t)blockIdx.x * 256 + threadIdx.x;
    if (idx >= (size_t)Np * Kp) return;
    int n = (int)(idx / Kp), k = (int)(idx % Kp);
    float v = (n < N && k < K) ? src[(size_t)n * K + k] : 0.f;
    dst[idx] = __float2bfloat16(v);
}

__global__ __launch_bounds__(256) void cast1d_kernel(
    const float* __restrict__ src, __hip_bfloat16* __restrict__ dst, int n)
{
    int idx = blockIdx.x * 256 + threadIdx.x;
    if (idx < n) dst[idx] = __float2bfloat16(src[idx]);
}

// ---------------------------------------------------------------------------
// bf16 MFMA GEMM: C(M,Np) = act(A(M,Kp) @ W(Np,Kp)^T + bias) [+ res].
// flags: bit0 relu; bit1 bf16 out; bit2 LSTM gate-interleave fp32 store
// C[m][(n&127)*4+(n>>7)] (Np==512); bit3 compact fp32 store at stride
// N_real, cols >= N_real dropped.
__global__ __launch_bounds__(256) void mfma_gemm(
    const __hip_bfloat16* __restrict__ A,
    const __hip_bfloat16* __restrict__ Wb,
    const float* __restrict__ bias,
    const float* __restrict__ res, int res_ld,
    void* __restrict__ Cout,
    int Np, int Kp, int N_real, int flags)
{
    __shared__ short As[128 * 32];
    __shared__ short Bs[128 * 32];
    const int tid  = threadIdx.x;
    const int wave = tid >> 6;
    const int lane = tid & 63;
    const int bm = blockIdx.y * 128, bn = blockIdx.x * 128;
    const int sr = lane >> 2;           // 0..15
    const int sc = (lane & 3) * 8;      // 0,8,16,24
    const int fr = lane & 15;
    const int fq = lane >> 4;           // quad
    const int wm = (wave >> 1) * 64, wn = (wave & 1) * 64;

    f32x4 acc[4][4];
#pragma unroll
    for (int i = 0; i < 4; ++i)
#pragma unroll
        for (int j = 0; j < 4; ++j) acc[i][j] = (f32x4){0.f, 0.f, 0.f, 0.f};

    const __hip_bfloat16* ga0 = A  + (size_t)(bm + wave * 32      + sr) * Kp + sc;
    const __hip_bfloat16* ga1 = A  + (size_t)(bm + wave * 32 + 16 + sr) * Kp + sc;
    const __hip_bfloat16* gb0 = Wb + (size_t)(bn + wave * 32      + sr) * Kp + sc;
    const __hip_bfloat16* gb1 = Wb + (size_t)(bn + wave * 32 + 16 + sr) * Kp + sc;
    short* lA0 = &As[(wave * 2 + 0) * 512];
    short* lA1 = &As[(wave * 2 + 1) * 512];
    short* lB0 = &Bs[(wave * 2 + 0) * 512];
    short* lB1 = &Bs[(wave * 2 + 1) * 512];

    for (int k0 = 0; k0 < Kp; k0 += 32) {
        gl_lds16(ga0 + k0, lA0);
        gl_lds16(ga1 + k0, lA1);
        gl_lds16(gb0 + k0, lB0);
        gl_lds16(gb1 + k0, lB1);
        __syncthreads();

        short8 af[4], bfr[4];
#pragma unroll
        for (int mi = 0; mi < 4; ++mi)
            af[mi] = *(const short8*)&As[(wm + mi * 16 + fr) * 32 + fq * 8];
#pragma unroll
        for (int ni = 0; ni < 4; ++ni)
            bfr[ni] = *(const short8*)&Bs[(wn + ni * 16 + fr) * 32 + fq * 8];
#pragma unroll
        for (int mi = 0; mi < 4; ++mi)
#pragma unroll
            for (int ni = 0; ni < 4; ++ni)
                acc[mi][ni] = __builtin_amdgcn_mfma_f32_16x16x32_bf16(
                    af[mi], bfr[ni], acc[mi][ni], 0, 0, 0);
        __syncthreads();
    }

    const bool relu = flags & 1;
    const bool obf  = flags & 2;
    const bool gate = flags & 4;
    const bool cmp  = flags & 8;
#pragma unroll
    for (int mi = 0; mi < 4; ++mi) {
#pragma unroll
        for (int ni = 0; ni < 4; ++ni) {
#pragma unroll
            for (int r = 0; r < 4; ++r) {
                int m = bm + wm + mi * 16 + fq * 4 + r;
                int n = bn + wn + ni * 16 + fr;
                float v = acc[mi][ni][r];
                if (n < N_real) {
                    v += bias[n];
                    if (relu) v = fmaxf(v, 0.f);
                    if (res) v += res[(size_t)m * res_ld + n];
                } else {
                    v = 0.f;
                }
                if (gate) {
                    ((float*)Cout)[(size_t)m * Np + ((n & 127) << 2) + (n >> 7)] = v;
                } else if (cmp) {
                    if (n < N_real)
                        ((float*)Cout)[(size_t)m * N_real + n] = v;
                } else if (obf) {
                    ((__hip_bfloat16*)Cout)[(size_t)m * Np + n] = __float2bfloat16(v);
                } else {
                    ((float*)Cout)[(size_t)m * Np + n] = v;
                }
            }
        }
    }
}

// ---------------------------------------------------------------------------
// Batched MFMA LSTM recurrence, 1024 threads (16 waves = 4/SIMD).
// Grid = 4 blocks: (dir, sample-half). Wave-groups 0 (waves 0-7) and 1
// (waves 8-15) duplicate the MFMA work (MFMA pipe is cold) but SPLIT the
// accumulator rows: group g handles r in {2g, 2g+1} -> per-lane
// transcendental work halves vs the 512-thread version, and 4 waves/SIMD
// hide the ds_read->MFMA->exp/rcp dependency chains (m114 co-schedule).
__global__ __launch_bounds__(1024, 4) void lstm_mfma_kernel(
    const float* __restrict__ pre_f, const float* __restrict__ pre_b,
    const __hip_bfloat16* __restrict__ whh_f,
    const __hip_bfloat16* __restrict__ whh_b,
    void* __restrict__ out, int out_bf16)   // out: (B,S,2*LH)
{
    const int dir = blockIdx.x >> 1;
    const int s0  = (blockIdx.x & 1) * 16;
    const float* pre = dir ? pre_b : pre_f;
    const __hip_bfloat16* whh = dir ? whh_b : whh_f;

    const int tid  = threadIdx.x;
    const int w16  = tid >> 6;          // 0..15
    const int grp  = w16 >> 3;          // 0/1 -> rows r0, r0+1
    const int w8   = w16 & 7;           // col-group 0..7
    const int lane = tid & 63;
    const int l15  = lane & 15;         // sample (A/C row)
    const int q    = lane >> 4;         // quad
    const int col  = 16 * w8 + l15;     // hidden index [0,128)
    const int r0   = grp * 2;

    // B fragments: bf[t][kt] = Whh[t*128+col][kt*32 + q*8 .. +7]
    short8 bf[4][4];
#pragma unroll
    for (int t = 0; t < 4; ++t) {
        const __hip_bfloat16* wrow = whh + (size_t)(t * 128 + col) * LH;
#pragma unroll
        for (int kt = 0; kt < 4; ++kt)
            bf[t][kt] = *(const short8*)(wrow + kt * 32 + q * 8);
    }

    // ping-pong h buffers, row stride 136 bf16 (pad 8)
    __shared__ __hip_bfloat16 h_lds[2][16][136];
    for (int i = tid; i < 2 * 16 * 136; i += 1024)
        ((__hip_bfloat16*)h_lds)[i] = __float2bfloat16(0.f);

    float c0 = 0.f, c1 = 0.f;

    // gate-interleaved pre: sample s0+4q+r0+{0,1}, col -> float4 (i,f,g,o)
    const float* pp0 = pre + ((size_t)(s0 + 4 * q + r0    ) * S + (dir ? (S - 1) : 0)) * G4 + col * 4;
    const float* pp1 = pre + ((size_t)(s0 + 4 * q + r0 + 1) * S + (dir ? (S - 1) : 0)) * G4 + col * 4;
    const int stepoff = dir ? -G4 : G4;

    float4 pc0 = *(const float4*)pp0;
    float4 pc1 = *(const float4*)pp1;

    barrier_lds();
    int p = 0;

    for (int step = 0; step < S; ++step) {
        // prefetch next step's pre (stays in flight across barrier_lds)
        float4 pn0 = make_float4(0.f, 0.f, 0.f, 0.f);
        float4 pn1 = pn0;
        if (step + 1 < S) {
            pp0 += stepoff; pp1 += stepoff;
            pn0 = *(const float4*)pp0;
            pn1 = *(const float4*)pp1;
        }

        // A fragments from LDS (full 128-wide h)
        short8 af[4];
#pragma unroll
        for (int kt = 0; kt < 4; ++kt)
            af[kt] = *(const short8*)&h_lds[p][l15][kt * 32 + q * 8];

        f32x4 acc[4];
#pragma unroll
        for (int t = 0; t < 4; ++t) {
            acc[t] = (f32x4){0.f, 0.f, 0.f, 0.f};
#pragma unroll
            for (int kt = 0; kt < 4; ++kt)
                acc[t] = __builtin_amdgcn_mfma_f32_16x16x32_bf16(
                    af[kt], bf[t][kt], acc[t], 0, 0, 0);
        }

        // select this group's two accumulator rows (grp is wave-uniform)
        float a0[4], a1[4];
#pragma unroll
        for (int t = 0; t < 4; ++t) {
            a0[t] = grp ? acc[t][2] : acc[t][0];
            a1[t] = grp ? acc[t][3] : acc[t][1];
        }

        const int tcur = dir ? (S - 1 - step) : step;
        float ig0 = fsigmoid(a0[0] + pc0.x);
        float fg0 = fsigmoid(a0[1] + pc0.y);
        float gg0 = ftanh   (a0[2] + pc0.z);
        float og0 = fsigmoid(a0[3] + pc0.w);
        c0 = fg0 * c0 + ig0 * gg0;
        float h0 = og0 * ftanh(c0);

        float ig1 = fsigmoid(a1[0] + pc1.x);
        float fg1 = fsigmoid(a1[1] + pc1.y);
        float gg1 = ftanh   (a1[2] + pc1.z);
        float og1 = fsigmoid(a1[3] + pc1.w);
        c1 = fg1 * c1 + ig1 * gg1;
        float h1 = og1 * ftanh(c1);

        __hip_bfloat16 hb0 = __float2bfloat16(h0);
        __hip_bfloat16 hb1 = __float2bfloat16(h1);
        h_lds[p ^ 1][4 * q + r0    ][col] = hb0;
        h_lds[p ^ 1][4 * q + r0 + 1][col] = hb1;

        size_t tok0 = (size_t)(s0 + 4 * q + r0    ) * S + tcur;
        size_t tok1 = (size_t)(s0 + 4 * q + r0 + 1) * S + tcur;
        if (out_bf16) {
            ((__hip_bfloat16*)out)[tok0 * 256 + dir * 128 + col] = hb0;
            ((__hip_bfloat16*)out)[tok1 * 256 + dir * 128 + col] = hb1;
        } else {
            ((float*)out)[tok0 * 256 + dir * 128 + col] = h0;
            ((float*)out)[tok1 * 256 + dir * 128 + col] = h1;
        }
        barrier_lds();
        p ^= 1;
        pc0 = pn0; pc1 = pn1;
    }
}

// ---------------------------------------------------------------------------
// CRF NLL per sample
__global__ __launch_bounds__(64) void crf_kernel(
    const float* __restrict__ em, const int* __restrict__ labels,
    const int* __restrict__ mask, const float* __restrict__ trans,
    float* __restrict__ nll)
{
    int b = blockIdx.x, tid = threadIdx.x;
    __shared__ float tr[NT * NT];
    __shared__ float alpha[NT];
    __shared__ float red[64];
    __shared__ float gold_s;

    for (int i = tid; i < NT * NT; i += 64) tr[i] = trans[i];
    __syncthreads();

    float emit = 0.f, pair = 0.f, lenf = 0.f;
    for (int s = tid; s < S; s += 64) {
        int lab = labels[b * S + s];
        float mf = (float)mask[b * S + s];
        emit += em[(size_t)(b * S + s) * NT + lab] * mf;
        lenf += mf;
        if (s >= 1) {
            int lp = labels[b * S + s - 1];
            pair += tr[lp * NT + lab] * mf;
        }
    }
    red[tid] = emit; __syncthreads();
    for (int st = 32; st > 0; st >>= 1) { if (tid < st) red[tid] += red[tid + st]; __syncthreads(); }
    float emit_tot = red[0]; __syncthreads();
    red[tid] = pair; __syncthreads();
    for (int st = 32; st > 0; st >>= 1) { if (tid < st) red[tid] += red[tid + st]; __syncthreads(); }
    float pair_tot = red[0]; __syncthreads();
    red[tid] = lenf; __syncthreads();
    for (int st = 32; st > 0; st >>= 1) { if (tid < st) red[tid] += red[tid + st]; __syncthreads(); }
    float len_tot = red[0]; __syncthreads();

    if (tid == 0) {
        int len_i = (int)(len_tot + 0.5f);
        int last = labels[b * S + len_i - 1];
        gold_s = tr[START_TAG * NT + labels[b * S]] + emit_tot + pair_tot
               + tr[last * NT + END_TAG];
    }
    if (tid < NT) alpha[tid] = tr[START_TAG * NT + tid] + em[(size_t)(b * S) * NT + tid];
    __syncthreads();

    for (int t = 1; t < S; ++t) {
        float newv = 0.f;
        if (tid < NT) {
            float vals[NT];
            float m = -1e30f;
#pragma unroll
            for (int i2 = 0; i2 < NT; ++i2) {
                float v = alpha[i2] + tr[i2 * NT + tid];
                vals[i2] = v;
                m = fmaxf(m, v);
            }
            float ssum = 0.f;
#pragma unroll
            for (int i2 = 0; i2 < NT; ++i2) ssum += __expf(vals[i2] - m);
            newv = m + __logf(ssum) + em[(size_t)(b * S + t) * NT + tid];
            if (!(mask[b * S + t] > 0)) newv = alpha[tid];
        }
        __syncthreads();
        if (tid < NT) alpha[tid] = newv;
        __syncthreads();
    }

    if (tid < NT) red[tid] = alpha[tid] + tr[tid * NT + END_TAG];
    __syncthreads();
    if (tid == 0) {
        float m = -1e30f;
        for (int j = 0; j < NT; ++j) m = fmaxf(m, red[j]);
        float ssum = 0.f;
        for (int j = 0; j < NT; ++j) ssum += __expf(red[j] - m);
        float logZ = m + __logf(ssum);
        nll[b] = logZ - gold_s;
    }
}

__global__ void mean_kernel(const float* __restrict__ nll, float* __restrict__ out)
{
    if (threadIdx.x == 0) {
        float s = 0.f;
        for (int i = 0; i < B; ++i) s += nll[i];
        out[0] = s / (float)B;
    }
}

// ---------------------------------------------------------------------------
extern "C" void kernel_launch(void* const* d_in, const int* in_sizes, int n_in,
                              void* d_out, int out_size, void* d_ws, size_t ws_size,
                              hipStream_t stream)
{
    const float* in_emb = (const float*)d_in[0];
    const int*   mask   = (const int*)d_in[1];
    const int*   labels = (const int*)d_in[2];
    const float* kg_W1  = (const float*)d_in[3];
    const float* kg_b1  = (const float*)d_in[4];
    const float* ln_g   = (const float*)d_in[5];
    const float* ln_b   = (const float*)d_in[6];
    const float* kg_W2  = (const float*)d_in[7];
    const float* kg_b2  = (const float*)d_in[8];
    const float* ff_W1  = (const float*)d_in[9];
    const float* ff_b1  = (const float*)d_in[10];
    const float* ff_W2  = (const float*)d_in[11];
    const float* ff_b2  = (const float*)d_in[12];
    const float* Wih0f  = (const float*)d_in[13];
    const float* Whh0f  = (const float*)d_in[14];
    const float* b0f    = (const float*)d_in[15];
    const float* Wih0b  = (const float*)d_in[16];
    const float* Whh0b  = (const float*)d_in[17];
    const float* b0b    = (const float*)d_in[18];
    const float* Wih1f  = (const float*)d_in[19];
    const float* Whh1f  = (const float*)d_in[20];
    const float* b1f    = (const float*)d_in[21];
    const float* Wih1b  = (const float*)d_in[22];
    const float* Whh1b  = (const float*)d_in[23];
    const float* b1b    = (const float*)d_in[24];
    const float* cls_W  = (const float*)d_in[25];
    const float* cls_b  = (const float*)d_in[26];
    const float* trans  = (const float*)d_in[27];
    (void)ws_size; (void)in_sizes; (void)n_in; (void)out_size;

    // ---- workspace arena ----
    char* wsb = (char*)d_ws;
    size_t o = 0;
    float*          comb32 = (float*)(wsb + o);            o += (size_t)M_TOK * D  * 4;
    __hip_bfloat16* Ab     = (__hip_bfloat16*)(wsb + o);   size_t ab_off = o; o += (size_t)M_TOK * DP * 2;
    char*           big    = wsb + o;                      o += (size_t)M_TOK * FF * 2;
    __hip_bfloat16* xb     = (__hip_bfloat16*)(wsb + o);   o += (size_t)M_TOK * DP * 2;
    __hip_bfloat16* Wbff1  = (__hip_bfloat16*)(wsb + o);   o += (size_t)FF * DP * 2;
    __hip_bfloat16* Wbff2  = (__hip_bfloat16*)(wsb + o);   o += (size_t)DP * FF * 2;
    __hip_bfloat16* Wb0f   = (__hip_bfloat16*)(wsb + o);   o += (size_t)G4 * DP * 2;
    __hip_bfloat16* Wb0b   = (__hip_bfloat16*)(wsb + o);   o += (size_t)G4 * DP * 2;
    __hip_bfloat16* Wb1f   = (__hip_bfloat16*)(wsb + o);   o += (size_t)G4 * 256 * 2;
    __hip_bfloat16* Wb1b   = (__hip_bfloat16*)(wsb + o);   o += (size_t)G4 * 256 * 2;
    __hip_bfloat16* Whb0f  = (__hip_bfloat16*)(wsb + o);   o += (size_t)G4 * LH * 2;
    __hip_bfloat16* Whb0b  = (__hip_bfloat16*)(wsb + o);   o += (size_t)G4 * LH * 2;
    __hip_bfloat16* Whb1f  = (__hip_bfloat16*)(wsb + o);   o += (size_t)G4 * LH * 2;
    __hip_bfloat16* Whb1b  = (__hip_bfloat16*)(wsb + o);   o += (size_t)G4 * LH * 2;
    __hip_bfloat16* Wbkg1  = (__hip_bfloat16*)(wsb + o);   o += (size_t)H * KGP * 2;
    __hip_bfloat16* Wbcls  = (__hip_bfloat16*)(wsb + o);   o += (size_t)128 * 256 * 2;
    float*          scores = (float*)(wsb + o);            o += (size_t)M_TOK * 4;
    float*          attw   = (float*)(wsb + o);            o += (size_t)M_TOK * 4;
    float*          emis   = (float*)(wsb + o);            o += (size_t)M_TOK * NT * 4;
    float*          nll    = (float*)(wsb + o);            o += B * 4;
    // big region reuse timeline:
    float*          h32   = (float*)(big + 0);                         // kg proj out
    __hip_bfloat16* Akg   = (__hip_bfloat16*)(big + 33554432);         // kg bf16 in
    __hip_bfloat16* ff1b  = (__hip_bfloat16*)big;                      // FF1 out
    float*          pre0f = (float*)(big + 0);                         // after FF2
    float*          pre0b = (float*)(big + 16777216);
    __hip_bfloat16* x1b   = (__hip_bfloat16*)(big + 33554432);         // LSTM0 out
    float*          pre1f = (float*)(big + 0);                         // after LSTM0
    float*          pre1b = (float*)(big + 16777216);
    __hip_bfloat16* x2b   = (__hip_bfloat16*)(wsb + ab_off);           // LSTM1 out (reuse Ab)

    // ---- weight casts ----
    castpad2d_kernel<<<(FF * DP + 255) / 256, 256, 0, stream>>>(ff_W1, Wbff1, FF, D,  FF, DP);
    castpad2d_kernel<<<(DP * FF + 255) / 256, 256, 0, stream>>>(ff_W2, Wbff2, D,  FF, DP, FF);
    castpad2d_kernel<<<(G4 * DP + 255) / 256, 256, 0, stream>>>(Wih0f, Wb0f, G4, D, G4, DP);
    castpad2d_kernel<<<(G4 * DP + 255) / 256, 256, 0, stream>>>(Wih0b, Wb0b, G4, D, G4, DP);
    castpad2d_kernel<<<(G4 * 256 + 255) / 256, 256, 0, stream>>>(Wih1f, Wb1f, G4, 256, G4, 256);
    castpad2d_kernel<<<(G4 * 256 + 255) / 256, 256, 0, stream>>>(Wih1b, Wb1b, G4, 256, G4, 256);
    cast1d_kernel<<<(G4 * LH + 255) / 256, 256, 0, stream>>>(Whh0f, Whb0f, G4 * LH);
    cast1d_kernel<<<(G4 * LH + 255) / 256, 256, 0, stream>>>(Whh0b, Whb0b, G4 * LH);
    cast1d_kernel<<<(G4 * LH + 255) / 256, 256, 0, stream>>>(Whh1f, Whb1f, G4 * LH);
    cast1d_kernel<<<(G4 * LH + 255) / 256, 256, 0, stream>>>(Whh1b, Whb1b, G4 * LH);
    castpad2d_kernel<<<(H * KGP + 255) / 256, 256, 0, stream>>>(kg_W1, Wbkg1, H, KG, H, KGP);
    castpad2d_kernel<<<(128 * 256 + 255) / 256, 256, 0, stream>>>(cls_W, Wbcls, NT, 256, 128, 256);

    // ---- attention front-end (kg proj via MFMA) ----
    castpad_kg_kernel<<<(M_TOK * KGP + 255) / 256, 256, 0, stream>>>(in_emb, Akg);
    mfma_gemm<<<dim3(H / 128, M_TOK / 128), 256, 0, stream>>>(
        Akg, Wbkg1, kg_b1, nullptr, 0, h32, H, KGP, H, 0);
    ln_score_kernel<<<M_TOK / 4, 256, 0, stream>>>(
        h32, ln_g, ln_b, kg_W2, kg_b2, scores);
    softmax_kernel<<<B, 256, 0, stream>>>(scores, attw);
    combine2_kernel<<<(M_TOK * DP + 255) / 256, 256, 0, stream>>>(in_emb, attw, comb32, Ab);

    // ---- FF block (bf16 MFMA) ----
    mfma_gemm<<<dim3(FF / 128, M_TOK / 128), 256, 0, stream>>>(
        Ab, Wbff1, ff_b1, nullptr, 0, ff1b, FF, DP, FF, 1 | 2);
    mfma_gemm<<<dim3(DP / 128, M_TOK / 128), 256, 0, stream>>>(
        ff1b, Wbff2, ff_b2, comb32, D, xb, DP, FF, D, 2);

    // ---- LSTM layer 0 (pre in gate-interleaved layout, flag 4) ----
    mfma_gemm<<<dim3(G4 / 128, M_TOK / 128), 256, 0, stream>>>(
        xb, Wb0f, b0f, nullptr, 0, pre0f, G4, DP, G4, 4);
    mfma_gemm<<<dim3(G4 / 128, M_TOK / 128), 256, 0, stream>>>(
        xb, Wb0b, b0b, nullptr, 0, pre0b, G4, DP, G4, 4);
    lstm_mfma_kernel<<<4, 1024, 0, stream>>>(pre0f, pre0b, Whb0f, Whb0b, x1b, 1);

    // ---- LSTM layer 1 ----
    mfma_gemm<<<dim3(G4 / 128, M_TOK / 128), 256, 0, stream>>>(
        x1b, Wb1f, b1f, nullptr, 0, pre1f, G4, 256, G4, 4);
    mfma_gemm<<<dim3(G4 / 128, M_TOK / 128), 256, 0, stream>>>(
        x1b, Wb1b, b1b, nullptr, 0, pre1b, G4, 256, G4, 4);
    lstm_mfma_kernel<<<4, 1024, 0, stream>>>(pre1f, pre1b, Whb1f, Whb1b, x2b, 1);

    // ---- emissions via MFMA (compact store, stride NT) + CRF + mean ----
    mfma_gemm<<<dim3(1, M_TOK / 128), 256, 0, stream>>>(
        x2b, Wbcls, cls_b, nullptr, 0, emis, 128, 256, NT, 8);
    crf_kernel<<<B, 64, 0, stream>>>(emis, labels, mask, trans, nll);
    mean_kernel<<<1, 64, 0, stream>>>(nll, (float*)d_out);
}